// Round 1
// baseline (5198.529 us; speedup 1.0000x reference)
//
#include <hip/hip_runtime.h>
#include <stdint.h>

// Exactness: the numpy/jax reference does plain IEEE f32 ops (no FMA
// contraction). hipcc defaults to -ffp-contract=fast; disable globally so
// IoU values match the reference bit-for-bit (labels depend on exact
// comparisons vs 0.3/0.7 and on ov == gt_max equality).
#pragma clang fp contract(off)

#define NBATCH 32
#define NK 50
#define NH 64
#define NW 64
#define NA 9
#define NN (NH * NW * NA)   // 36864 anchors per batch
#define BN (NBATCH * NN)    // 1179648
#define HWSZ (NH * NW)      // 4096

// ---------------- workspace layout (bytes) ----------------
constexpr size_t OFF_MAXOV = 0;
constexpr size_t OFF_AMAX  = OFF_MAXOV + (size_t)BN * 4;
constexpr size_t OFF_LABEL = OFF_AMAX + (size_t)BN * 4;
constexpr size_t OFF_GTMAX = OFF_LABEL + (size_t)BN * 4;
constexpr size_t OFF_FGTOT = OFF_GTMAX + (size_t)NBATCH * NK * 4;  // zero-region start
constexpr size_t OFF_BGTOT = OFF_FGTOT + NBATCH * 4;
constexpr size_t OFF_NUMEX = OFF_BGTOT + NBATCH * 4;
constexpr size_t OFF_H1FG  = OFF_NUMEX + NBATCH * 4;
constexpr size_t OFF_H1BG  = OFF_H1FG + (size_t)NBATCH * 4096 * 4;
constexpr size_t WS_END    = OFF_H1BG + (size_t)NBATCH * 4096 * 4;
constexpr size_t ZERO_LEN  = WS_END - OFF_FGTOT;

// ---------------- output layout (f32 elements) ----------------
constexpr size_t OUT_LAB  = 0;
constexpr size_t OUT_TGT  = (size_t)NBATCH * NA * HWSZ;                 // 1179648
constexpr size_t OUT_INW  = OUT_TGT + (size_t)NBATCH * NA * 4 * HWSZ;   // 5898240
constexpr size_t OUT_OUTW = OUT_INW + (size_t)NBATCH * NA * 4 * HWSZ;   // 10616832

// 9 base anchors, py-faster-rcnn generate_anchors(16, (0.5,1,2), (8,16,32)),
// ratio-major scale-minor. All integer-valued -> exact in f32.
__constant__ float c_anch[NA][4] = {
    {-84.f, -40.f, 99.f, 55.f},    {-176.f, -88.f, 191.f, 103.f},
    {-360.f, -184.f, 375.f, 199.f}, {-56.f, -56.f, 71.f, 71.f},
    {-120.f, -120.f, 135.f, 135.f}, {-248.f, -248.f, 263.f, 263.f},
    {-36.f, -80.f, 51.f, 95.f},    {-80.f, -168.f, 95.f, 183.f},
    {-168.f, -344.f, 183.f, 359.f}};

// ---------------- Threefry-2x32 (JAX convention) ----------------
struct TF2 { uint32_t a, b; };

__host__ __device__ constexpr uint32_t rotl32(uint32_t x, int d) {
  return (x << d) | (x >> (32 - d));
}

__host__ __device__ constexpr TF2 threefry2x32(uint32_t k0, uint32_t k1,
                                               uint32_t x0, uint32_t x1) {
  uint32_t ks2 = k0 ^ k1 ^ 0x1BD11BDAu;
  x0 += k0; x1 += k1;
  x0 += x1; x1 = rotl32(x1, 13); x1 ^= x0;
  x0 += x1; x1 = rotl32(x1, 15); x1 ^= x0;
  x0 += x1; x1 = rotl32(x1, 26); x1 ^= x0;
  x0 += x1; x1 = rotl32(x1, 6);  x1 ^= x0;
  x0 += k1; x1 += ks2 + 1u;
  x0 += x1; x1 = rotl32(x1, 17); x1 ^= x0;
  x0 += x1; x1 = rotl32(x1, 29); x1 ^= x0;
  x0 += x1; x1 = rotl32(x1, 16); x1 ^= x0;
  x0 += x1; x1 = rotl32(x1, 24); x1 ^= x0;
  x0 += ks2; x1 += k0 + 2u;
  x0 += x1; x1 = rotl32(x1, 13); x1 ^= x0;
  x0 += x1; x1 = rotl32(x1, 15); x1 ^= x0;
  x0 += x1; x1 = rotl32(x1, 26); x1 ^= x0;
  x0 += x1; x1 = rotl32(x1, 6);  x1 ^= x0;
  x0 += k0; x1 += k1 + 3u;
  x0 += x1; x1 = rotl32(x1, 17); x1 ^= x0;
  x0 += x1; x1 = rotl32(x1, 29); x1 ^= x0;
  x0 += x1; x1 = rotl32(x1, 16); x1 ^= x0;
  x0 += x1; x1 = rotl32(x1, 24); x1 ^= x0;
  x0 += k1; x1 += ks2 + 4u;
  x0 += x1; x1 = rotl32(x1, 13); x1 ^= x0;
  x0 += x1; x1 = rotl32(x1, 15); x1 ^= x0;
  x0 += x1; x1 = rotl32(x1, 26); x1 ^= x0;
  x0 += x1; x1 = rotl32(x1, 6);  x1 ^= x0;
  x0 += ks2; x1 += k0 + 5u;
  return TF2{x0, x1};
}

// jax.random.key(42) = (0,42); split with jax_threefry_partitionable=True:
// subkey i = threefry(key, counter=(0, i)).
constexpr TF2 KEY_FG = threefry2x32(0u, 42u, 0u, 0u);
constexpr TF2 KEY_BG = threefry2x32(0u, 42u, 0u, 1u);

// 32-bit draw at flat index i (partitionable): bits = out.a ^ out.b of
// threefry(key, hi32(i)=0, lo32(i)=i). Ranking score for uniform() is
// monotone+injective in bits>>9, so compare the 23-bit value directly.
__device__ inline uint32_t rand23(uint32_t k0, uint32_t k1, uint32_t idx) {
  TF2 r = threefry2x32(k0, k1, 0u, idx);
  return (r.a ^ r.b) >> 9;
}

// ---------------- geometry ----------------
__device__ inline void anchor_of(int n, float& x1, float& y1, float& x2, float& y2) {
  int a = n % NA;
  int s = n / NA;
  int xx = s % NW;
  int yy = s / NW;
  float sx = (float)(xx * 16);
  float sy = (float)(yy * 16);
  x1 = c_anch[a][0] + sx; y1 = c_anch[a][1] + sy;
  x2 = c_anch[a][2] + sx; y2 = c_anch[a][3] + sy;
}

__device__ inline float iou1(float ax1, float ay1, float ax2, float ay2,
                             float gx1, float gy1, float gx2, float gy2) {
  float iw = fminf(ax2, gx2) - fmaxf(ax1, gx1) + 1.0f;
  iw = fmaxf(iw, 0.0f);
  float ih = fminf(ay2, gy2) - fmaxf(ay1, gy1) + 1.0f;
  ih = fmaxf(ih, 0.0f);
  float inter = iw * ih;
  float aa = (ax2 - ax1 + 1.0f) * (ay2 - ay1 + 1.0f);
  float ga = (gx2 - gx1 + 1.0f) * (gy2 - gy1 + 1.0f);
  return inter / (aa + ga - inter);
}

// ---------------- K1: per-anchor max IoU + argmax ----------------
__global__ __launch_bounds__(256) void k_iou(const float* __restrict__ gt,
                                             const int* __restrict__ nbox,
                                             float* __restrict__ maxov,
                                             int* __restrict__ amax) {
  int t = blockIdx.x * 256 + threadIdx.x;
  if (t >= BN) return;
  int b = t / NN;
  int n = t - b * NN;
  float ax1, ay1, ax2, ay2;
  anchor_of(n, ax1, ay1, ax2, ay2);
  int m = nbox[b];
  const float* g = gt + (size_t)b * NK * 5;
  float best = -2.0f;
  int bi = 0;
  for (int k = 0; k < m; ++k) {
    float ov = iou1(ax1, ay1, ax2, ay2, g[k * 5], g[k * 5 + 1], g[k * 5 + 2], g[k * 5 + 3]);
    if (ov > best) { best = ov; bi = k; }
  }
  maxov[t] = best;
  amax[t] = bi;
}

// ---------------- K1b: per-gt max IoU over all anchors ----------------
__global__ __launch_bounds__(256) void k_gtmax(const float* __restrict__ gt,
                                               const int* __restrict__ nbox,
                                               float* __restrict__ gtmax) {
  int b = blockIdx.x / NK;
  int k = blockIdx.x % NK;
  if (k >= nbox[b]) {
    if (threadIdx.x == 0) gtmax[blockIdx.x] = -1.0f;
    return;
  }
  const float* g = gt + ((size_t)b * NK + k) * 5;
  float gx1 = g[0], gy1 = g[1], gx2 = g[2], gy2 = g[3];
  float m = -1.0f;
  for (int n = threadIdx.x; n < NN; n += 256) {
    float ax1, ay1, ax2, ay2;
    anchor_of(n, ax1, ay1, ax2, ay2);
    m = fmaxf(m, iou1(ax1, ay1, ax2, ay2, gx1, gy1, gx2, gy2));
  }
  for (int o = 1; o < 64; o <<= 1) m = fmaxf(m, __shfl_xor(m, o));
  __shared__ float ws4[4];
  if ((threadIdx.x & 63) == 0) ws4[threadIdx.x >> 6] = m;
  __syncthreads();
  if (threadIdx.x == 0) {
    m = fmaxf(fmaxf(ws4[0], ws4[1]), fmaxf(ws4[2], ws4[3]));
    if (m == 0.0f) m = 1e-5f;  // reference: gt_max==0 -> 1e-5
    gtmax[blockIdx.x] = m;
  }
}

// ---------------- K2: labels + per-batch fg/bg counts + level-1 hist ----------------
__global__ __launch_bounds__(256) void k_label(const float* __restrict__ gt,
                                               const int* __restrict__ nbox,
                                               const float* __restrict__ maxov,
                                               const float* __restrict__ gtmax,
                                               const float* __restrict__ iminfo,
                                               int* __restrict__ label,
                                               int* __restrict__ fgtot,
                                               int* __restrict__ bgtot,
                                               unsigned* __restrict__ h1fg,
                                               unsigned* __restrict__ h1bg) {
  int t = blockIdx.x * 256 + threadIdx.x;
  if (t >= BN) return;
  int b = t / NN;
  int n = t - b * NN;
  float ax1, ay1, ax2, ay2;
  anchor_of(n, ax1, ay1, ax2, ay2);
  float imh = iminfo[0], imw = iminfo[1];  // im_info[0] used for all batches (matches ref)
  bool inside = (ax1 >= 0.0f) && (ay1 >= 0.0f) && (ax2 < imw) && (ay2 < imh);
  int lab = -1;
  if (inside) {
    float mo = maxov[t];
    if (mo < 0.3f) lab = 0;
    int m = nbox[b];
    const float* g = gt + (size_t)b * NK * 5;
    const float* gm = gtmax + (size_t)b * NK;
    bool best = false;
    for (int k = 0; k < m; ++k) {
      float ov = iou1(ax1, ay1, ax2, ay2, g[k * 5], g[k * 5 + 1], g[k * 5 + 2], g[k * 5 + 3]);
      if (ov == gm[k]) best = true;
    }
    if (best) lab = 1;
    if (mo >= 0.7f) lab = 1;
  }
  label[t] = lab;
  if (lab == 1) {
    atomicAdd(&fgtot[b], 1);
    uint32_t v = rand23(KEY_FG.a, KEY_FG.b, (uint32_t)t);
    atomicAdd(&h1fg[b * 4096 + (v >> 11)], 1u);
  } else if (lab == 0) {
    atomicAdd(&bgtot[b], 1);
    uint32_t v = rand23(KEY_BG.a, KEY_BG.b, (uint32_t)t);
    atomicAdd(&h1bg[b * 4096 + (v >> 11)], 1u);
  }
}

// ---------------- K3: exact stable top-C subsampling ----------------
// One block per (batch, class). Selection = top-C by (23-bit score desc,
// index asc) == jax's stable rank of -score. Two-level histogram finds the
// threshold value v*; an ordered block scan breaks ties by smallest index.
__global__ __launch_bounds__(256) void k_select(int* __restrict__ label,
                                                const int* __restrict__ fgtot,
                                                const int* __restrict__ bgtot,
                                                const unsigned* __restrict__ h1fg,
                                                const unsigned* __restrict__ h1bg,
                                                float* __restrict__ numex) {
  int b = blockIdx.x >> 1;
  int cls = blockIdx.x & 1;  // 0 = fg, 1 = bg
  int fg = fgtot[b], bg = bgtot[b];
  int fgk = min(fg, 128);
  int total, C, want;
  uint32_t kk0, kk1;
  const unsigned* h1;
  if (cls == 0) {
    total = fg; C = 128; want = 1; kk0 = KEY_FG.a; kk1 = KEY_FG.b; h1 = h1fg + (size_t)b * 4096;
    if (threadIdx.x == 0) {
      int bgk = min(bg, 256 - fgk);
      numex[b] = (float)(fgk + bgk);  // analytic (lab>=0).sum() after subsample
    }
  } else {
    total = bg; C = 256 - fgk; want = 0; kk0 = KEY_BG.a; kk1 = KEY_BG.b; h1 = h1bg + (size_t)b * 4096;
  }
  if (total <= C) return;  // keep all (ranks 0..total-1 < C)

  __shared__ unsigned h1s[4096];
  __shared__ unsigned h2[2048];
  __shared__ int sBstar, sR1, sLstar, sR2;
  for (int i = threadIdx.x; i < 4096; i += 256) h1s[i] = h1[i];
  for (int i = threadIdx.x; i < 2048; i += 256) h2[i] = 0;
  __syncthreads();
  if (threadIdx.x == 0) {
    int cum = 0, Bs = 0, r1 = C;
    for (int i = 4095; i >= 0; --i) {
      int c = (int)h1s[i];
      if (cum + c >= C) { Bs = i; r1 = C - cum; break; }
      cum += c;
    }
    sBstar = Bs; sR1 = r1;
  }
  __syncthreads();
  int Bs = sBstar, r1 = sR1;
  int base_lab = b * NN;
  for (int n = threadIdx.x; n < NN; n += 256) {
    if (label[base_lab + n] == want) {
      uint32_t v = rand23(kk0, kk1, (uint32_t)(base_lab + n));
      if ((int)(v >> 11) == Bs) atomicAdd(&h2[v & 2047u], 1u);
    }
  }
  __syncthreads();
  if (threadIdx.x == 0) {
    int cum = 0, Ls = 0, r2 = r1;
    for (int j = 2047; j >= 0; --j) {
      int c = (int)h2[j];
      if (cum + c >= r1) { Ls = j; r2 = r1 - cum; break; }
      cum += c;
    }
    sLstar = Ls; sR2 = r2;
  }
  __syncthreads();
  uint32_t vstar = ((uint32_t)Bs << 11) | (uint32_t)sLstar;
  unsigned r2 = (unsigned)sR2;

  // Ordered scan: demote (set -1) masked anchors with v < v*, and all but
  // the first r2 (by index) anchors with v == v*.
  __shared__ unsigned wsum[4];
  __shared__ unsigned running;
  if (threadIdx.x == 0) running = 0;
  __syncthreads();
  int lane = threadIdx.x & 63, wid = threadIdx.x >> 6;
  for (int base = 0; base < NN; base += 256) {  // NN % 256 == 0
    int li = base_lab + base + threadIdx.x;
    bool mask = (label[li] == want);
    uint32_t v = 0;
    if (mask) v = rand23(kk0, kk1, (uint32_t)li);
    bool eq = mask && (v == vstar);
    unsigned long long bal = __ballot(eq);
    if (lane == 0) wsum[wid] = (unsigned)__popcll(bal);
    __syncthreads();
    unsigned off = running;
    for (int w = 0; w < wid; ++w) off += wsum[w];
    unsigned rank = off + (unsigned)__popcll(bal & ((1ull << lane) - 1ull));
    if (mask && ((v < vstar) || (eq && rank >= r2))) label[li] = -1;
    __syncthreads();
    if (threadIdx.x == 0) running += wsum[0] + wsum[1] + wsum[2] + wsum[3];
    __syncthreads();
  }
}

// ---------------- K4: write all four outputs ----------------
__global__ __launch_bounds__(256) void k_out(const float* __restrict__ gt,
                                             const int* __restrict__ label,
                                             const int* __restrict__ amax,
                                             const float* __restrict__ iminfo,
                                             const float* __restrict__ numex,
                                             float* __restrict__ out) {
  int t = blockIdx.x * 256 + threadIdx.x;
  if (t >= (int)OUT_TGT) return;  // B*A*H*W threads, output-major
  int xx = t & 63;
  int yy = (t >> 6) & 63;
  int ba = t >> 12;
  int a = ba % NA;
  int b = ba / NA;
  int yx = yy * NW + xx;
  int n = yx * NA + a;
  int bn = b * NN + n;
  int lab = label[bn];

  out[OUT_LAB + t] = (float)lab;

  float ax1, ay1, ax2, ay2;
  anchor_of(n, ax1, ay1, ax2, ay2);
  float imh = iminfo[0], imw = iminfo[1];
  bool inside = (ax1 >= 0.0f) && (ay1 >= 0.0f) && (ax2 < imw) && (ay2 < imh);
  float t0 = 0.f, t1 = 0.f, t2 = 0.f, t3 = 0.f;
  if (inside) {
    const float* g = gt + ((size_t)b * NK + amax[bn]) * 5;
    float ew = ax2 - ax1 + 1.0f, eh = ay2 - ay1 + 1.0f;
    float ecx = ax1 + 0.5f * ew, ecy = ay1 + 0.5f * eh;
    float gw = g[2] - g[0] + 1.0f, gh = g[3] - g[1] + 1.0f;
    float gcx = g[0] + 0.5f * gw, gcy = g[1] + 0.5f * gh;
    t0 = (gcx - ecx) / ew;
    t1 = (gcy - ecy) / eh;
    t2 = logf(gw / ew);
    t3 = logf(gh / eh);
  }
  size_t tb = OUT_TGT + ((size_t)b * NA * 4 + a * 4) * HWSZ + yx;
  out[tb] = t0; out[tb + HWSZ] = t1; out[tb + 2 * HWSZ] = t2; out[tb + 3 * HWSZ] = t3;

  float iw_ = (lab == 1) ? 1.0f : 0.0f;
  size_t ib = OUT_INW + ((size_t)b * NA * 4 + a * 4) * HWSZ + yx;
  out[ib] = iw_; out[ib + HWSZ] = iw_; out[ib + 2 * HWSZ] = iw_; out[ib + 3 * HWSZ] = iw_;

  float ow_ = (lab >= 0) ? (1.0f / numex[b]) : 0.0f;
  size_t ob = OUT_OUTW + ((size_t)b * NA * 4 + a * 4) * HWSZ + yx;
  out[ob] = ow_; out[ob + HWSZ] = ow_; out[ob + 2 * HWSZ] = ow_; out[ob + 3 * HWSZ] = ow_;
}

extern "C" void kernel_launch(void* const* d_in, const int* in_sizes, int n_in,
                              void* d_out, int out_size, void* d_ws, size_t ws_size,
                              hipStream_t stream) {
  (void)in_sizes; (void)n_in; (void)out_size; (void)ws_size;
  const float* gt     = (const float*)d_in[1];  // (B,K,5)
  const float* iminfo = (const float*)d_in[2];  // (B,3)
  const int*   nbox   = (const int*)d_in[3];    // (B,)
  float* out = (float*)d_out;
  char* ws = (char*)d_ws;

  float*    maxov = (float*)(ws + OFF_MAXOV);
  int*      amax  = (int*)(ws + OFF_AMAX);
  int*      label = (int*)(ws + OFF_LABEL);
  float*    gtmax = (float*)(ws + OFF_GTMAX);
  int*      fgtot = (int*)(ws + OFF_FGTOT);
  int*      bgtot = (int*)(ws + OFF_BGTOT);
  float*    numex = (float*)(ws + OFF_NUMEX);
  unsigned* h1fg  = (unsigned*)(ws + OFF_H1FG);
  unsigned* h1bg  = (unsigned*)(ws + OFF_H1BG);

  // ws is re-poisoned to 0xAA before every launch: zero counters + histograms.
  hipMemsetAsync(ws + OFF_FGTOT, 0, ZERO_LEN, stream);

  k_iou<<<(BN + 255) / 256, 256, 0, stream>>>(gt, nbox, maxov, amax);
  k_gtmax<<<NBATCH * NK, 256, 0, stream>>>(gt, nbox, gtmax);
  k_label<<<(BN + 255) / 256, 256, 0, stream>>>(gt, nbox, maxov, gtmax, iminfo,
                                                label, fgtot, bgtot, h1fg, h1bg);
  k_select<<<2 * NBATCH, 256, 0, stream>>>(label, fgtot, bgtot, h1fg, h1bg, numex);
  k_out<<<(int)((OUT_TGT + 255) / 256), 256, 0, stream>>>(gt, label, amax, iminfo, numex, out);
}

// Round 2
// 388.313 us; speedup vs baseline: 13.3875x; 13.3875x over previous
//
#include <hip/hip_runtime.h>
#include <stdint.h>

// Exactness: the numpy/jax reference does plain IEEE f32 ops (no FMA
// contraction). hipcc defaults to -ffp-contract=fast; disable globally so
// IoU values match the reference bit-for-bit (labels depend on exact
// comparisons vs 0.3/0.7 and on ov == gt_max equality).
#pragma clang fp contract(off)

#define NBATCH 32
#define NK 50
#define NH 64
#define NW 64
#define NA 9
#define NN (NH * NW * NA)   // 36864 anchors per batch
#define BN (NBATCH * NN)    // 1179648
#define HWSZ (NH * NW)      // 4096

// ---------------- workspace layout (bytes) ----------------
// No global counters/histograms anymore -> no memset, no global atomics.
constexpr size_t OFF_AMAX  = 0;
constexpr size_t OFF_LABEL = OFF_AMAX + (size_t)BN * 4;
constexpr size_t OFF_GTMAX = OFF_LABEL + (size_t)BN * 4;
constexpr size_t OFF_NUMEX = OFF_GTMAX + (size_t)NBATCH * NK * 4;

// ---------------- output layout (f32 elements) ----------------
constexpr size_t OUT_LAB  = 0;
constexpr size_t OUT_TGT  = (size_t)NBATCH * NA * HWSZ;                 // 1179648
constexpr size_t OUT_INW  = OUT_TGT + (size_t)NBATCH * NA * 4 * HWSZ;   // 5898240
constexpr size_t OUT_OUTW = OUT_INW + (size_t)NBATCH * NA * 4 * HWSZ;   // 10616832

// 9 base anchors, py-faster-rcnn generate_anchors(16, (0.5,1,2), (8,16,32)),
// ratio-major scale-minor. All integer-valued -> exact in f32.
__constant__ float c_anch[NA][4] = {
    {-84.f, -40.f, 99.f, 55.f},    {-176.f, -88.f, 191.f, 103.f},
    {-360.f, -184.f, 375.f, 199.f}, {-56.f, -56.f, 71.f, 71.f},
    {-120.f, -120.f, 135.f, 135.f}, {-248.f, -248.f, 263.f, 263.f},
    {-36.f, -80.f, 51.f, 95.f},    {-80.f, -168.f, 95.f, 183.f},
    {-168.f, -344.f, 183.f, 359.f}};

// ---------------- Threefry-2x32 (JAX convention) ----------------
struct TF2 { uint32_t a, b; };

__host__ __device__ constexpr uint32_t rotl32(uint32_t x, int d) {
  return (x << d) | (x >> (32 - d));
}

__host__ __device__ constexpr TF2 threefry2x32(uint32_t k0, uint32_t k1,
                                               uint32_t x0, uint32_t x1) {
  uint32_t ks2 = k0 ^ k1 ^ 0x1BD11BDAu;
  x0 += k0; x1 += k1;
  x0 += x1; x1 = rotl32(x1, 13); x1 ^= x0;
  x0 += x1; x1 = rotl32(x1, 15); x1 ^= x0;
  x0 += x1; x1 = rotl32(x1, 26); x1 ^= x0;
  x0 += x1; x1 = rotl32(x1, 6);  x1 ^= x0;
  x0 += k1; x1 += ks2 + 1u;
  x0 += x1; x1 = rotl32(x1, 17); x1 ^= x0;
  x0 += x1; x1 = rotl32(x1, 29); x1 ^= x0;
  x0 += x1; x1 = rotl32(x1, 16); x1 ^= x0;
  x0 += x1; x1 = rotl32(x1, 24); x1 ^= x0;
  x0 += ks2; x1 += k0 + 2u;
  x0 += x1; x1 = rotl32(x1, 13); x1 ^= x0;
  x0 += x1; x1 = rotl32(x1, 15); x1 ^= x0;
  x0 += x1; x1 = rotl32(x1, 26); x1 ^= x0;
  x0 += x1; x1 = rotl32(x1, 6);  x1 ^= x0;
  x0 += k0; x1 += k1 + 3u;
  x0 += x1; x1 = rotl32(x1, 17); x1 ^= x0;
  x0 += x1; x1 = rotl32(x1, 29); x1 ^= x0;
  x0 += x1; x1 = rotl32(x1, 16); x1 ^= x0;
  x0 += x1; x1 = rotl32(x1, 24); x1 ^= x0;
  x0 += k1; x1 += ks2 + 4u;
  x0 += x1; x1 = rotl32(x1, 13); x1 ^= x0;
  x0 += x1; x1 = rotl32(x1, 15); x1 ^= x0;
  x0 += x1; x1 = rotl32(x1, 26); x1 ^= x0;
  x0 += x1; x1 = rotl32(x1, 6);  x1 ^= x0;
  x0 += ks2; x1 += k0 + 5u;
  return TF2{x0, x1};
}

// jax.random.key(42) = (0,42); split with jax_threefry_partitionable=True:
// subkey i = threefry(key, counter=(0, i)).
constexpr TF2 KEY_FG = threefry2x32(0u, 42u, 0u, 0u);
constexpr TF2 KEY_BG = threefry2x32(0u, 42u, 0u, 1u);

// 32-bit draw at flat index i (partitionable): bits = out.a ^ out.b of
// threefry(key, hi32(i)=0, lo32(i)=i). Ranking score for uniform() is
// monotone+injective in bits>>9, so compare the 23-bit value directly.
__device__ inline uint32_t rand23(uint32_t k0, uint32_t k1, uint32_t idx) {
  TF2 r = threefry2x32(k0, k1, 0u, idx);
  return (r.a ^ r.b) >> 9;
}

// ---------------- geometry ----------------
__device__ inline void anchor_of(int n, float& x1, float& y1, float& x2, float& y2) {
  int a = n % NA;
  int s = n / NA;
  int xx = s % NW;
  int yy = s / NW;
  float sx = (float)(xx * 16);
  float sy = (float)(yy * 16);
  x1 = c_anch[a][0] + sx; y1 = c_anch[a][1] + sy;
  x2 = c_anch[a][2] + sx; y2 = c_anch[a][3] + sy;
}

__device__ inline float iou1(float ax1, float ay1, float ax2, float ay2,
                             float gx1, float gy1, float gx2, float gy2) {
  float iw = fminf(ax2, gx2) - fmaxf(ax1, gx1) + 1.0f;
  iw = fmaxf(iw, 0.0f);
  float ih = fminf(ay2, gy2) - fmaxf(ay1, gy1) + 1.0f;
  ih = fmaxf(ih, 0.0f);
  float inter = iw * ih;
  float aa = (ax2 - ax1 + 1.0f) * (ay2 - ay1 + 1.0f);
  float ga = (gx2 - gx1 + 1.0f) * (gy2 - gy1 + 1.0f);
  return inter / (aa + ga - inter);
}

// ---------------- K1: per-gt max IoU over all anchors ----------------
__global__ __launch_bounds__(256) void k_gtmax(const float* __restrict__ gt,
                                               const int* __restrict__ nbox,
                                               float* __restrict__ gtmax) {
  int b = blockIdx.x / NK;
  int k = blockIdx.x % NK;
  if (k >= nbox[b]) {
    if (threadIdx.x == 0) gtmax[blockIdx.x] = -1.0f;
    return;
  }
  const float* g = gt + ((size_t)b * NK + k) * 5;
  float gx1 = g[0], gy1 = g[1], gx2 = g[2], gy2 = g[3];
  float m = -1.0f;
  for (int n = threadIdx.x; n < NN; n += 256) {
    float ax1, ay1, ax2, ay2;
    anchor_of(n, ax1, ay1, ax2, ay2);
    m = fmaxf(m, iou1(ax1, ay1, ax2, ay2, gx1, gy1, gx2, gy2));
  }
  for (int o = 1; o < 64; o <<= 1) m = fmaxf(m, __shfl_xor(m, o));
  __shared__ float ws4[4];
  if ((threadIdx.x & 63) == 0) ws4[threadIdx.x >> 6] = m;
  __syncthreads();
  if (threadIdx.x == 0) {
    m = fmaxf(fmaxf(ws4[0], ws4[1]), fmaxf(ws4[2], ws4[3]));
    if (m == 0.0f) m = 1e-5f;  // reference: gt_max==0 -> 1e-5
    gtmax[blockIdx.x] = m;
  }
}

// ---------------- K2: merged IoU + labels (NO atomics) ----------------
// One IoU pass per anchor computes max/argmax and the ov==gt_max best check.
__global__ __launch_bounds__(256) void k_label(const float* __restrict__ gt,
                                               const int* __restrict__ nbox,
                                               const float* __restrict__ gtmax,
                                               const float* __restrict__ iminfo,
                                               int* __restrict__ label,
                                               int* __restrict__ amax) {
  int t = blockIdx.x * 256 + threadIdx.x;
  if (t >= BN) return;
  int b = t / NN;
  int n = t - b * NN;
  float ax1, ay1, ax2, ay2;
  anchor_of(n, ax1, ay1, ax2, ay2);
  int m = nbox[b];
  const float* g = gt + (size_t)b * NK * 5;
  const float* gm = gtmax + (size_t)b * NK;
  float best = -2.0f;
  int bi = 0;
  bool isbest = false;
  for (int k = 0; k < m; ++k) {
    float ov = iou1(ax1, ay1, ax2, ay2, g[k * 5], g[k * 5 + 1], g[k * 5 + 2], g[k * 5 + 3]);
    if (ov > best) { best = ov; bi = k; }   // first-max wins, like argmax
    if (ov == gm[k]) isbest = true;
  }
  float imh = iminfo[0], imw = iminfo[1];  // im_info[0] used for all batches (matches ref)
  bool inside = (ax1 >= 0.0f) && (ay1 >= 0.0f) && (ax2 < imw) && (ay2 < imh);
  int lab = -1;
  if (inside) {
    if (best < 0.3f) lab = 0;
    if (isbest) lab = 1;
    if (best >= 0.7f) lab = 1;
  }
  label[t] = lab;
  amax[t] = bi;
}

// ---------------- K3: exact stable top-C subsampling (self-contained) ----
// One block per (batch, class). Builds its own LDS histogram + fg/bg counts
// (no global atomics anywhere). Selection = top-C by (23-bit score desc,
// index asc) == jax's stable rank of -score. Two-level histogram finds the
// threshold value v*; an ordered block scan breaks ties by smallest index.
__global__ __launch_bounds__(256) void k_select(int* __restrict__ label,
                                                float* __restrict__ numex) {
  int b = blockIdx.x >> 1;
  int cls = blockIdx.x & 1;  // 0 = fg, 1 = bg
  int base_lab = b * NN;
  int want = (cls == 0) ? 1 : 0;
  uint32_t kk0 = (cls == 0) ? KEY_FG.a : KEY_BG.a;
  uint32_t kk1 = (cls == 0) ? KEY_FG.b : KEY_BG.b;

  __shared__ unsigned h1s[4096];
  __shared__ unsigned h2[2048];
  __shared__ unsigned coarse[256];
  __shared__ int sFG, sBG;
  __shared__ int sBstar, sR1, sLstar, sR2;
  for (int i = threadIdx.x; i < 4096; i += 256) h1s[i] = 0;
  for (int i = threadIdx.x; i < 2048; i += 256) h2[i] = 0;
  if (threadIdx.x == 0) { sFG = 0; sBG = 0; }
  __syncthreads();

  // Pass 1: count fg/bg and build level-1 histogram for our class.
  int cfg = 0, cbg = 0;
  for (int n = threadIdx.x; n < NN; n += 256) {  // NN % 256 == 0
    int lab = label[base_lab + n];
    cfg += (lab == 1);
    cbg += (lab == 0);
    if (lab == want) {
      uint32_t v = rand23(kk0, kk1, (uint32_t)(base_lab + n));
      atomicAdd(&h1s[v >> 11], 1u);  // LDS atomic, low contention
    }
  }
  for (int o = 1; o < 64; o <<= 1) { cfg += __shfl_xor(cfg, o); cbg += __shfl_xor(cbg, o); }
  if ((threadIdx.x & 63) == 0) { atomicAdd(&sFG, cfg); atomicAdd(&sBG, cbg); }
  __syncthreads();

  int fg = sFG, bg = sBG;
  int fgk = min(fg, 128);
  int total, C;
  if (cls == 0) {
    total = fg; C = 128;
  } else {
    total = bg; C = 256 - fgk;
    if (threadIdx.x == 0) numex[b] = (float)(fgk + min(bg, C));  // analytic num_examples
  }
  if (total <= C) return;  // keep all (ranks 0..total-1 < C); uniform exit

  // Level-1 threshold: largest bucket Bs with suffix count >= C.
  unsigned s1 = 0;
  for (int j = 0; j < 16; ++j) s1 += h1s[threadIdx.x * 16 + j];
  coarse[threadIdx.x] = s1;
  __syncthreads();
  if (threadIdx.x == 0) {
    int cum = 0, cb = 255;
    for (; cb > 0; --cb) { int c = (int)coarse[cb]; if (cum + c >= C) break; cum += c; }
    int i = cb * 16 + 15;
    for (; i > cb * 16; --i) { int c = (int)h1s[i]; if (cum + c >= C) break; cum += c; }
    if (i == cb * 16) { /* falls in first slot of chunk */ }
    sBstar = i; sR1 = C - cum;
  }
  __syncthreads();
  int Bs = sBstar, r1 = sR1;

  // Pass 2: level-2 histogram restricted to bucket Bs.
  for (int n = threadIdx.x; n < NN; n += 256) {
    if (label[base_lab + n] == want) {
      uint32_t v = rand23(kk0, kk1, (uint32_t)(base_lab + n));
      if ((int)(v >> 11) == Bs) atomicAdd(&h2[v & 2047u], 1u);
    }
  }
  __syncthreads();
  unsigned s2 = 0;
  for (int j = 0; j < 8; ++j) s2 += h2[threadIdx.x * 8 + j];
  coarse[threadIdx.x] = s2;
  __syncthreads();
  if (threadIdx.x == 0) {
    int cum = 0, cb = 255;
    for (; cb > 0; --cb) { int c = (int)coarse[cb]; if (cum + c >= r1) break; cum += c; }
    int j = cb * 8 + 7;
    for (; j > cb * 8; --j) { int c = (int)h2[j]; if (cum + c >= r1) break; cum += c; }
    sLstar = j; sR2 = r1 - cum;
  }
  __syncthreads();
  uint32_t vstar = ((uint32_t)Bs << 11) | (uint32_t)sLstar;
  unsigned r2 = (unsigned)sR2;

  // Pass 3 (ordered scan): demote masked anchors with v < v*, and all but
  // the first r2 (by ascending index) anchors with v == v*.
  __shared__ unsigned wsum[4];
  __shared__ unsigned running;
  if (threadIdx.x == 0) running = 0;
  __syncthreads();
  int lane = threadIdx.x & 63, wid = threadIdx.x >> 6;
  for (int base = 0; base < NN; base += 256) {  // NN % 256 == 0
    int li = base_lab + base + threadIdx.x;
    bool mask = (label[li] == want);
    uint32_t v = 0;
    if (mask) v = rand23(kk0, kk1, (uint32_t)li);
    bool eq = mask && (v == vstar);
    unsigned long long bal = __ballot(eq);
    if (lane == 0) wsum[wid] = (unsigned)__popcll(bal);
    __syncthreads();
    unsigned off = running;
    for (int w = 0; w < wid; ++w) off += wsum[w];
    unsigned rank = off + (unsigned)__popcll(bal & ((1ull << lane) - 1ull));
    if (mask && ((v < vstar) || (eq && rank >= r2))) label[li] = -1;
    __syncthreads();
    if (threadIdx.x == 0) running += wsum[0] + wsum[1] + wsum[2] + wsum[3];
    __syncthreads();
  }
}

// ---------------- K4: write all four outputs ----------------
__global__ __launch_bounds__(256) void k_out(const float* __restrict__ gt,
                                             const int* __restrict__ label,
                                             const int* __restrict__ amax,
                                             const float* __restrict__ iminfo,
                                             const float* __restrict__ numex,
                                             float* __restrict__ out) {
  int t = blockIdx.x * 256 + threadIdx.x;
  if (t >= (int)OUT_TGT) return;  // B*A*H*W threads, output-major
  int xx = t & 63;
  int yy = (t >> 6) & 63;
  int ba = t >> 12;
  int a = ba % NA;
  int b = ba / NA;
  int yx = yy * NW + xx;
  int n = yx * NA + a;
  int bn = b * NN + n;
  int lab = label[bn];

  out[OUT_LAB + t] = (float)lab;

  float ax1, ay1, ax2, ay2;
  anchor_of(n, ax1, ay1, ax2, ay2);
  float imh = iminfo[0], imw = iminfo[1];
  bool inside = (ax1 >= 0.0f) && (ay1 >= 0.0f) && (ax2 < imw) && (ay2 < imh);
  float t0 = 0.f, t1 = 0.f, t2 = 0.f, t3 = 0.f;
  if (inside) {
    const float* g = gt + ((size_t)b * NK + amax[bn]) * 5;
    float ew = ax2 - ax1 + 1.0f, eh = ay2 - ay1 + 1.0f;
    float ecx = ax1 + 0.5f * ew, ecy = ay1 + 0.5f * eh;
    float gw = g[2] - g[0] + 1.0f, gh = g[3] - g[1] + 1.0f;
    float gcx = g[0] + 0.5f * gw, gcy = g[1] + 0.5f * gh;
    t0 = (gcx - ecx) / ew;
    t1 = (gcy - ecy) / eh;
    t2 = logf(gw / ew);
    t3 = logf(gh / eh);
  }
  size_t tb = OUT_TGT + ((size_t)b * NA * 4 + a * 4) * HWSZ + yx;
  out[tb] = t0; out[tb + HWSZ] = t1; out[tb + 2 * HWSZ] = t2; out[tb + 3 * HWSZ] = t3;

  float iw_ = (lab == 1) ? 1.0f : 0.0f;
  size_t ib = OUT_INW + ((size_t)b * NA * 4 + a * 4) * HWSZ + yx;
  out[ib] = iw_; out[ib + HWSZ] = iw_; out[ib + 2 * HWSZ] = iw_; out[ib + 3 * HWSZ] = iw_;

  float ow_ = (lab >= 0) ? (1.0f / numex[b]) : 0.0f;
  size_t ob = OUT_OUTW + ((size_t)b * NA * 4 + a * 4) * HWSZ + yx;
  out[ob] = ow_; out[ob + HWSZ] = ow_; out[ob + 2 * HWSZ] = ow_; out[ob + 3 * HWSZ] = ow_;
}

extern "C" void kernel_launch(void* const* d_in, const int* in_sizes, int n_in,
                              void* d_out, int out_size, void* d_ws, size_t ws_size,
                              hipStream_t stream) {
  (void)in_sizes; (void)n_in; (void)out_size; (void)ws_size;
  const float* gt     = (const float*)d_in[1];  // (B,K,5)
  const float* iminfo = (const float*)d_in[2];  // (B,3)
  const int*   nbox   = (const int*)d_in[3];    // (B,)
  float* out = (float*)d_out;
  char* ws = (char*)d_ws;

  int*   amax  = (int*)(ws + OFF_AMAX);
  int*   label = (int*)(ws + OFF_LABEL);
  float* gtmax = (float*)(ws + OFF_GTMAX);
  float* numex = (float*)(ws + OFF_NUMEX);

  k_gtmax<<<NBATCH * NK, 256, 0, stream>>>(gt, nbox, gtmax);
  k_label<<<(BN + 255) / 256, 256, 0, stream>>>(gt, nbox, gtmax, iminfo, label, amax);
  k_select<<<2 * NBATCH, 256, 0, stream>>>(label, numex);
  k_out<<<(int)((OUT_TGT + 255) / 256), 256, 0, stream>>>(gt, label, amax, iminfo, numex, out);
}

// Round 3
// 245.806 us; speedup vs baseline: 21.1489x; 1.5798x over previous
//
#include <hip/hip_runtime.h>
#include <stdint.h>

// Exactness: the numpy/jax reference does plain IEEE f32 ops (no FMA
// contraction). hipcc defaults to -ffp-contract=fast; disable globally so
// IoU values match the reference bit-for-bit (labels depend on exact
// comparisons vs 0.3/0.7 and on ov == gt_max equality).
#pragma clang fp contract(off)

#define NBATCH 32
#define NK 50
#define NH 64
#define NW 64
#define NA 9
#define NN (NH * NW * NA)   // 36864 anchors per batch
#define BN (NBATCH * NN)    // 1179648
#define HWSZ (NH * NW)      // 4096
#define BLK_PER_B (NN / 256)  // 144 label-blocks per batch

// ---------------- workspace layout (bytes) ----------------
constexpr size_t OFF_AMAX  = 0;
constexpr size_t OFF_LABEL = OFF_AMAX + (size_t)BN * 4;
constexpr size_t OFF_GTMAX = OFF_LABEL + (size_t)BN * 4;
constexpr size_t OFF_NUMEX = OFF_GTMAX + (size_t)NBATCH * NK * 4;

// ---------------- output layout (f32 elements) ----------------
constexpr size_t OUT_LAB  = 0;
constexpr size_t OUT_TGT  = (size_t)NBATCH * NA * HWSZ;                 // 1179648
constexpr size_t OUT_INW  = OUT_TGT + (size_t)NBATCH * NA * 4 * HWSZ;   // 5898240
constexpr size_t OUT_OUTW = OUT_INW + (size_t)NBATCH * NA * 4 * HWSZ;   // 10616832

// 9 base anchors, py-faster-rcnn generate_anchors(16, (0.5,1,2), (8,16,32)),
// ratio-major scale-minor. All integer-valued -> exact in f32.
__constant__ float c_anch[NA][4] = {
    {-84.f, -40.f, 99.f, 55.f},    {-176.f, -88.f, 191.f, 103.f},
    {-360.f, -184.f, 375.f, 199.f}, {-56.f, -56.f, 71.f, 71.f},
    {-120.f, -120.f, 135.f, 135.f}, {-248.f, -248.f, 263.f, 263.f},
    {-36.f, -80.f, 51.f, 95.f},    {-80.f, -168.f, 95.f, 183.f},
    {-168.f, -344.f, 183.f, 359.f}};

// ---------------- Threefry-2x32 (JAX convention) ----------------
struct TF2 { uint32_t a, b; };

__host__ __device__ constexpr uint32_t rotl32(uint32_t x, int d) {
  return (x << d) | (x >> (32 - d));
}

__host__ __device__ constexpr TF2 threefry2x32(uint32_t k0, uint32_t k1,
                                               uint32_t x0, uint32_t x1) {
  uint32_t ks2 = k0 ^ k1 ^ 0x1BD11BDAu;
  x0 += k0; x1 += k1;
  x0 += x1; x1 = rotl32(x1, 13); x1 ^= x0;
  x0 += x1; x1 = rotl32(x1, 15); x1 ^= x0;
  x0 += x1; x1 = rotl32(x1, 26); x1 ^= x0;
  x0 += x1; x1 = rotl32(x1, 6);  x1 ^= x0;
  x0 += k1; x1 += ks2 + 1u;
  x0 += x1; x1 = rotl32(x1, 17); x1 ^= x0;
  x0 += x1; x1 = rotl32(x1, 29); x1 ^= x0;
  x0 += x1; x1 = rotl32(x1, 16); x1 ^= x0;
  x0 += x1; x1 = rotl32(x1, 24); x1 ^= x0;
  x0 += ks2; x1 += k0 + 2u;
  x0 += x1; x1 = rotl32(x1, 13); x1 ^= x0;
  x0 += x1; x1 = rotl32(x1, 15); x1 ^= x0;
  x0 += x1; x1 = rotl32(x1, 26); x1 ^= x0;
  x0 += x1; x1 = rotl32(x1, 6);  x1 ^= x0;
  x0 += k0; x1 += k1 + 3u;
  x0 += x1; x1 = rotl32(x1, 17); x1 ^= x0;
  x0 += x1; x1 = rotl32(x1, 29); x1 ^= x0;
  x0 += x1; x1 = rotl32(x1, 16); x1 ^= x0;
  x0 += x1; x1 = rotl32(x1, 24); x1 ^= x0;
  x0 += k1; x1 += ks2 + 4u;
  x0 += x1; x1 = rotl32(x1, 13); x1 ^= x0;
  x0 += x1; x1 = rotl32(x1, 15); x1 ^= x0;
  x0 += x1; x1 = rotl32(x1, 26); x1 ^= x0;
  x0 += x1; x1 = rotl32(x1, 6);  x1 ^= x0;
  x0 += ks2; x1 += k0 + 5u;
  return TF2{x0, x1};
}

// jax.random.key(42) = (0,42); split with jax_threefry_partitionable=True:
// subkey i = threefry(key, counter=(0, i)).
constexpr TF2 KEY_FG = threefry2x32(0u, 42u, 0u, 0u);
constexpr TF2 KEY_BG = threefry2x32(0u, 42u, 0u, 1u);

// 32-bit draw at flat index i (partitionable): bits = out.a ^ out.b of
// threefry(key, hi32(i)=0, lo32(i)=i). Ranking score for uniform() is
// monotone+injective in bits>>9, so compare the 23-bit value directly.
__device__ inline uint32_t rand23(uint32_t k0, uint32_t k1, uint32_t idx) {
  TF2 r = threefry2x32(k0, k1, 0u, idx);
  return (r.a ^ r.b) >> 9;
}

// ---------------- geometry ----------------
__device__ inline void anchor_of(int n, float& x1, float& y1, float& x2, float& y2) {
  int a = n % NA;
  int s = n / NA;
  int xx = s % NW;
  int yy = s / NW;
  float sx = (float)(xx * 16);
  float sy = (float)(yy * 16);
  x1 = c_anch[a][0] + sx; y1 = c_anch[a][1] + sy;
  x2 = c_anch[a][2] + sx; y2 = c_anch[a][3] + sy;
}

__device__ inline float iou1(float ax1, float ay1, float ax2, float ay2,
                             float gx1, float gy1, float gx2, float gy2) {
  float iw = fminf(ax2, gx2) - fmaxf(ax1, gx1) + 1.0f;
  iw = fmaxf(iw, 0.0f);
  float ih = fminf(ay2, gy2) - fmaxf(ay1, gy1) + 1.0f;
  ih = fmaxf(ih, 0.0f);
  float inter = iw * ih;
  float aa = (ax2 - ax1 + 1.0f) * (ay2 - ay1 + 1.0f);
  float ga = (gx2 - gx1 + 1.0f) * (gy2 - gy1 + 1.0f);
  return inter / (aa + ga - inter);
}

// ---------------- K1: per-gt max IoU over all anchors ----------------
__global__ __launch_bounds__(256) void k_gtmax(const float* __restrict__ gt,
                                               const int* __restrict__ nbox,
                                               float* __restrict__ gtmax) {
  int b = blockIdx.x / NK;
  int k = blockIdx.x % NK;
  if (k >= nbox[b]) {
    if (threadIdx.x == 0) gtmax[blockIdx.x] = -1.0f;
    return;
  }
  const float* g = gt + ((size_t)b * NK + k) * 5;
  float gx1 = g[0], gy1 = g[1], gx2 = g[2], gy2 = g[3];
  float m = -1.0f;
  for (int n = threadIdx.x; n < NN; n += 256) {
    float ax1, ay1, ax2, ay2;
    anchor_of(n, ax1, ay1, ax2, ay2);
    m = fmaxf(m, iou1(ax1, ay1, ax2, ay2, gx1, gy1, gx2, gy2));
  }
  for (int o = 1; o < 64; o <<= 1) m = fmaxf(m, __shfl_xor(m, o));
  __shared__ float ws4[4];
  if ((threadIdx.x & 63) == 0) ws4[threadIdx.x >> 6] = m;
  __syncthreads();
  if (threadIdx.x == 0) {
    m = fmaxf(fmaxf(ws4[0], ws4[1]), fmaxf(ws4[2], ws4[3]));
    if (m == 0.0f) m = 1e-5f;  // reference: gt_max==0 -> 1e-5
    gtmax[blockIdx.x] = m;
  }
}

// ---------------- K2: merged IoU + labels (gt/gtmax staged in LDS) -------
__global__ __launch_bounds__(256) void k_label(const float* __restrict__ gt,
                                               const int* __restrict__ nbox,
                                               const float* __restrict__ gtmax,
                                               const float* __restrict__ iminfo,
                                               int* __restrict__ label,
                                               int* __restrict__ amax) {
  int b = blockIdx.x / BLK_PER_B;                // block-uniform batch index
  int n = (blockIdx.x % BLK_PER_B) * 256 + threadIdx.x;
  __shared__ float sg[NK * 5];
  __shared__ float sgm[NK];
  if (threadIdx.x < NK * 5) sg[threadIdx.x] = gt[(size_t)b * NK * 5 + threadIdx.x];
  if (threadIdx.x < NK) sgm[threadIdx.x] = gtmax[b * NK + threadIdx.x];
  __syncthreads();

  float ax1, ay1, ax2, ay2;
  anchor_of(n, ax1, ay1, ax2, ay2);
  int m = nbox[b];
  float best = -2.0f;
  int bi = 0;
  bool isbest = false;
  for (int k = 0; k < m; ++k) {
    float ov = iou1(ax1, ay1, ax2, ay2, sg[k * 5], sg[k * 5 + 1], sg[k * 5 + 2], sg[k * 5 + 3]);
    if (ov > best) { best = ov; bi = k; }   // first-max wins, like argmax
    if (ov == sgm[k]) isbest = true;
  }
  float imh = iminfo[0], imw = iminfo[1];  // im_info[0] used for all batches (matches ref)
  bool inside = (ax1 >= 0.0f) && (ay1 >= 0.0f) && (ax2 < imw) && (ay2 < imh);
  int lab = -1;
  if (inside) {
    if (best < 0.3f) lab = 0;
    if (isbest) lab = 1;
    if (best >= 0.7f) lab = 1;
  }
  int t = b * NN + n;
  label[t] = lab;
  amax[t] = bi;
}

// ---------------- K3: exact stable top-C subsampling -------------------
// One 1024-thread block per (batch, class). Two vectorized passes:
//   P1: count fg/bg + 4096-bucket LDS histogram of the 23-bit scores.
//   (parallel suffix-scan finds threshold bucket Bs and within-bucket rank r1)
//   P2: demote bucket<Bs inline; collect bucket==Bs ties into an LDS list.
// Exact stable top-r1 among ties by (v desc, idx asc) via O(L^2) rank.
// Equivalent to jax's stable rank of -uniform() (argsort-argsort).
__global__ __launch_bounds__(1024) void k_select(int* __restrict__ label,
                                                 float* __restrict__ numex) {
  int b = blockIdx.x >> 1;
  int cls = blockIdx.x & 1;  // 0 = fg, 1 = bg
  int base_lab = b * NN;
  int want = (cls == 0) ? 1 : 0;
  uint32_t kk0 = (cls == 0) ? KEY_FG.a : KEY_BG.a;
  uint32_t kk1 = (cls == 0) ? KEY_FG.b : KEY_BG.b;
  int tid = threadIdx.x;

  __shared__ unsigned h1s[4096];
  __shared__ unsigned listV[2048];
  __shared__ unsigned listI[2048];
  __shared__ unsigned waveTot[4];
  __shared__ int sFG, sBG, sBs, sR1, sCross;
  __shared__ unsigned sCnt;
  for (int i = tid; i < 4096; i += 1024) h1s[i] = 0;
  if (tid == 0) { sFG = 0; sBG = 0; sCross = -1; sCnt = 0; }
  __syncthreads();

  const int4* lab4 = (const int4*)(label + base_lab);

  // ---- Pass 1: fg/bg counts + level-1 histogram ----
  int cfg = 0, cbg = 0;
  for (int i = tid; i < NN / 4; i += 1024) {
    int4 L4 = lab4[i];
    int labs[4] = {L4.x, L4.y, L4.z, L4.w};
#pragma unroll
    for (int j = 0; j < 4; ++j) {
      int lab = labs[j];
      cfg += (lab == 1);
      cbg += (lab == 0);
      if (lab == want) {
        uint32_t v = rand23(kk0, kk1, (uint32_t)(base_lab + 4 * i + j));
        atomicAdd(&h1s[v >> 11], 1u);
      }
    }
  }
  for (int o = 1; o < 64; o <<= 1) { cfg += __shfl_xor(cfg, o); cbg += __shfl_xor(cbg, o); }
  if ((tid & 63) == 0) { atomicAdd(&sFG, cfg); atomicAdd(&sBG, cbg); }
  __syncthreads();

  int fg = sFG, bg = sBG;
  int fgk = min(fg, 128);
  int total, C;
  if (cls == 0) {
    total = fg; C = 128;
  } else {
    total = bg; C = 256 - fgk;
    if (tid == 0) numex[b] = (float)(fgk + min(bg, C));  // analytic num_examples
  }
  if (total <= C) return;  // keep all; uniform exit across block

  // ---- Parallel threshold: largest bucket Bs with suffix count >= C ----
  unsigned myChunk = 0, suf = 0;
  if (tid < 256) {
    for (int j = 0; j < 16; ++j) myChunk += h1s[tid * 16 + j];
    unsigned ss = myChunk;
    int lane = tid & 63;
#pragma unroll
    for (int o = 1; o < 64; o <<= 1) {
      unsigned t2 = __shfl_down(ss, o);
      if (lane + o < 64) ss += t2;
    }
    suf = ss;  // partial: suffix within this wave's chunk range
    if (lane == 0) waveTot[tid >> 6] = ss;
  }
  __syncthreads();
  if (tid < 256) {
    int w = tid >> 6;
    for (int w2 = w + 1; w2 < 4; ++w2) suf += waveTot[w2];
    // suf = S[16*tid] = count of scores in buckets >= 16*tid
    if (suf >= (unsigned)C) atomicMax(&sCross, tid);
  }
  __syncthreads();
  if (tid == sCross) {
    unsigned cum = suf - myChunk;  // S[16*(tid+1)]
    int i = tid * 16 + 15;
    for (;; --i) {
      unsigned c = h1s[i];
      if (cum + c >= (unsigned)C) break;
      cum += c;
    }
    sBs = i; sR1 = (int)((unsigned)C - cum);
  }
  __syncthreads();
  int Bs = sBs;
  unsigned r1 = (unsigned)sR1;

  // ---- Pass 2: demote bucket<Bs, collect bucket==Bs ties ----
  for (int i = tid; i < NN / 4; i += 1024) {
    int4 L4 = lab4[i];
    int labs[4] = {L4.x, L4.y, L4.z, L4.w};
#pragma unroll
    for (int j = 0; j < 4; ++j) {
      if (labs[j] == want) {
        int n = 4 * i + j;
        uint32_t v = rand23(kk0, kk1, (uint32_t)(base_lab + n));
        int bk = (int)(v >> 11);
        if (bk < Bs) {
          label[base_lab + n] = -1;
        } else if (bk == Bs) {
          unsigned p = atomicAdd(&sCnt, 1u);
          if (p < 2048u) { listV[p] = v; listI[p] = (unsigned)n; }
        }
      }
    }
  }
  __syncthreads();

  // ---- Exact stable top-r1 among ties: rank by (v desc, idx asc) ----
  unsigned L = min(sCnt, 2048u);
  for (unsigned i = tid; i < L; i += 1024) {
    unsigned vi = listV[i], xi = listI[i];
    unsigned rank = 0;
    for (unsigned j = 0; j < L; ++j) {
      unsigned vj = listV[j], xj = listI[j];
      rank += (vj > vi) || (vj == vi && xj < xi);
    }
    if (rank >= r1) label[base_lab + (int)xi] = -1;
  }
}

// ---------------- K4: write all four outputs (float4 stores) ----------
__global__ __launch_bounds__(256) void k_out(const float* __restrict__ gt,
                                             const int* __restrict__ label,
                                             const int* __restrict__ amax,
                                             const float* __restrict__ iminfo,
                                             const float* __restrict__ numex,
                                             float* __restrict__ out) {
  int q = blockIdx.x * 256 + threadIdx.x;
  if (q >= (int)(OUT_TGT / 4)) return;
  int xx4 = q & 15;
  int yy = (q >> 4) & 63;
  int ba = q >> 10;
  int a = ba % NA;
  int b = ba / NA;
  int xx0 = xx4 * 4;
  int yx0 = yy * NW + xx0;

  float imh = iminfo[0], imw = iminfo[1];
  float inv_ne = 1.0f / numex[b];

  float labf[4], iwv[4], owv[4], tg[4][4];
#pragma unroll
  for (int u = 0; u < 4; ++u) {
    int xx = xx0 + u;
    int n = (yy * NW + xx) * NA + a;
    int bn = b * NN + n;
    int lab = label[bn];
    labf[u] = (float)lab;
    float ax1, ay1, ax2, ay2;
    anchor_of(n, ax1, ay1, ax2, ay2);
    bool inside = (ax1 >= 0.0f) && (ay1 >= 0.0f) && (ax2 < imw) && (ay2 < imh);
    float t0 = 0.f, t1 = 0.f, t2 = 0.f, t3 = 0.f;
    if (inside) {
      const float* g = gt + ((size_t)b * NK + amax[bn]) * 5;
      float ew = ax2 - ax1 + 1.0f, eh = ay2 - ay1 + 1.0f;
      float ecx = ax1 + 0.5f * ew, ecy = ay1 + 0.5f * eh;
      float gw = g[2] - g[0] + 1.0f, gh = g[3] - g[1] + 1.0f;
      float gcx = g[0] + 0.5f * gw, gcy = g[1] + 0.5f * gh;
      t0 = (gcx - ecx) / ew;
      t1 = (gcy - ecy) / eh;
      t2 = logf(gw / ew);
      t3 = logf(gh / eh);
    }
    tg[0][u] = t0; tg[1][u] = t1; tg[2][u] = t2; tg[3][u] = t3;
    iwv[u] = (lab == 1) ? 1.0f : 0.0f;
    owv[u] = (lab >= 0) ? inv_ne : 0.0f;
  }

  *(float4*)(out + OUT_LAB + (size_t)ba * HWSZ + yx0) =
      make_float4(labf[0], labf[1], labf[2], labf[3]);
  size_t tb = OUT_TGT + ((size_t)b * NA * 4 + a * 4) * HWSZ + yx0;
#pragma unroll
  for (int d = 0; d < 4; ++d)
    *(float4*)(out + tb + (size_t)d * HWSZ) =
        make_float4(tg[d][0], tg[d][1], tg[d][2], tg[d][3]);
  size_t ib = OUT_INW + ((size_t)b * NA * 4 + a * 4) * HWSZ + yx0;
  float4 iw4 = make_float4(iwv[0], iwv[1], iwv[2], iwv[3]);
#pragma unroll
  for (int d = 0; d < 4; ++d) *(float4*)(out + ib + (size_t)d * HWSZ) = iw4;
  size_t ob = OUT_OUTW + ((size_t)b * NA * 4 + a * 4) * HWSZ + yx0;
  float4 ow4 = make_float4(owv[0], owv[1], owv[2], owv[3]);
#pragma unroll
  for (int d = 0; d < 4; ++d) *(float4*)(out + ob + (size_t)d * HWSZ) = ow4;
}

extern "C" void kernel_launch(void* const* d_in, const int* in_sizes, int n_in,
                              void* d_out, int out_size, void* d_ws, size_t ws_size,
                              hipStream_t stream) {
  (void)in_sizes; (void)n_in; (void)out_size; (void)ws_size;
  const float* gt     = (const float*)d_in[1];  // (B,K,5)
  const float* iminfo = (const float*)d_in[2];  // (B,3)
  const int*   nbox   = (const int*)d_in[3];    // (B,)
  float* out = (float*)d_out;
  char* ws = (char*)d_ws;

  int*   amax  = (int*)(ws + OFF_AMAX);
  int*   label = (int*)(ws + OFF_LABEL);
  float* gtmax = (float*)(ws + OFF_GTMAX);
  float* numex = (float*)(ws + OFF_NUMEX);

  k_gtmax<<<NBATCH * NK, 256, 0, stream>>>(gt, nbox, gtmax);
  k_label<<<BN / 256, 256, 0, stream>>>(gt, nbox, gtmax, iminfo, label, amax);
  k_select<<<2 * NBATCH, 1024, 0, stream>>>(label, numex);
  k_out<<<(int)(OUT_TGT / 4 / 256), 256, 0, stream>>>(gt, label, amax, iminfo, numex, out);
}

// Round 4
// 195.247 us; speedup vs baseline: 26.6254x; 1.2589x over previous
//
#include <hip/hip_runtime.h>
#include <stdint.h>

// Exactness: the numpy/jax reference does plain IEEE f32 ops (no FMA
// contraction). hipcc defaults to -ffp-contract=fast; disable globally so
// IoU values match the reference bit-for-bit (labels depend on exact
// comparisons vs 0.3/0.7 and on ov == gt_max equality).
#pragma clang fp contract(off)

#define NBATCH 32
#define NK 50
#define NH 64
#define NW 64
#define NA 9
#define NN (NH * NW * NA)   // 36864 anchors per batch
#define BN (NBATCH * NN)    // 1179648
#define HWSZ (NH * NW)      // 4096
#define BLK_PER_B (NN / 256)  // 144 label-blocks per batch

// ---------------- workspace layout (bytes) ----------------
constexpr size_t OFF_AMAX  = 0;
constexpr size_t OFF_LABEL = OFF_AMAX + (size_t)BN * 4;
constexpr size_t OFF_GTMAX = OFF_LABEL + (size_t)BN * 4;
constexpr size_t OFF_NUMEX = OFF_GTMAX + (size_t)NBATCH * NK * 4;

// ---------------- output layout (f32 elements) ----------------
constexpr size_t OUT_LAB  = 0;
constexpr size_t OUT_TGT  = (size_t)NBATCH * NA * HWSZ;                 // 1179648
constexpr size_t OUT_INW  = OUT_TGT + (size_t)NBATCH * NA * 4 * HWSZ;   // 5898240
constexpr size_t OUT_OUTW = OUT_INW + (size_t)NBATCH * NA * 4 * HWSZ;   // 10616832

// 9 base anchors, py-faster-rcnn generate_anchors(16, (0.5,1,2), (8,16,32)),
// ratio-major scale-minor. All integer-valued -> exact in f32.
__constant__ float c_anch[NA][4] = {
    {-84.f, -40.f, 99.f, 55.f},    {-176.f, -88.f, 191.f, 103.f},
    {-360.f, -184.f, 375.f, 199.f}, {-56.f, -56.f, 71.f, 71.f},
    {-120.f, -120.f, 135.f, 135.f}, {-248.f, -248.f, 263.f, 263.f},
    {-36.f, -80.f, 51.f, 95.f},    {-80.f, -168.f, 95.f, 183.f},
    {-168.f, -344.f, 183.f, 359.f}};

// ---------------- Threefry-2x32 (JAX convention) ----------------
struct TF2 { uint32_t a, b; };

__host__ __device__ constexpr uint32_t rotl32(uint32_t x, int d) {
  return (x << d) | (x >> (32 - d));
}

__host__ __device__ constexpr TF2 threefry2x32(uint32_t k0, uint32_t k1,
                                               uint32_t x0, uint32_t x1) {
  uint32_t ks2 = k0 ^ k1 ^ 0x1BD11BDAu;
  x0 += k0; x1 += k1;
  x0 += x1; x1 = rotl32(x1, 13); x1 ^= x0;
  x0 += x1; x1 = rotl32(x1, 15); x1 ^= x0;
  x0 += x1; x1 = rotl32(x1, 26); x1 ^= x0;
  x0 += x1; x1 = rotl32(x1, 6);  x1 ^= x0;
  x0 += k1; x1 += ks2 + 1u;
  x0 += x1; x1 = rotl32(x1, 17); x1 ^= x0;
  x0 += x1; x1 = rotl32(x1, 29); x1 ^= x0;
  x0 += x1; x1 = rotl32(x1, 16); x1 ^= x0;
  x0 += x1; x1 = rotl32(x1, 24); x1 ^= x0;
  x0 += ks2; x1 += k0 + 2u;
  x0 += x1; x1 = rotl32(x1, 13); x1 ^= x0;
  x0 += x1; x1 = rotl32(x1, 15); x1 ^= x0;
  x0 += x1; x1 = rotl32(x1, 26); x1 ^= x0;
  x0 += x1; x1 = rotl32(x1, 6);  x1 ^= x0;
  x0 += k0; x1 += k1 + 3u;
  x0 += x1; x1 = rotl32(x1, 17); x1 ^= x0;
  x0 += x1; x1 = rotl32(x1, 29); x1 ^= x0;
  x0 += x1; x1 = rotl32(x1, 16); x1 ^= x0;
  x0 += x1; x1 = rotl32(x1, 24); x1 ^= x0;
  x0 += k1; x1 += ks2 + 4u;
  x0 += x1; x1 = rotl32(x1, 13); x1 ^= x0;
  x0 += x1; x1 = rotl32(x1, 15); x1 ^= x0;
  x0 += x1; x1 = rotl32(x1, 26); x1 ^= x0;
  x0 += x1; x1 = rotl32(x1, 6);  x1 ^= x0;
  x0 += ks2; x1 += k0 + 5u;
  return TF2{x0, x1};
}

// jax.random.key(42) = (0,42); split with jax_threefry_partitionable=True:
// subkey i = threefry(key, counter=(0, i)).
constexpr TF2 KEY_FG = threefry2x32(0u, 42u, 0u, 0u);
constexpr TF2 KEY_BG = threefry2x32(0u, 42u, 0u, 1u);

// 32-bit draw at flat index i (partitionable): bits = out.a ^ out.b of
// threefry(key, hi32(i)=0, lo32(i)=i). Ranking score for uniform() is
// monotone+injective in bits>>9, so compare the 23-bit value directly.
__device__ inline uint32_t rand23(uint32_t k0, uint32_t k1, uint32_t idx) {
  TF2 r = threefry2x32(k0, k1, 0u, idx);
  return (r.a ^ r.b) >> 9;
}

// ---------------- geometry ----------------
__device__ inline void anchor_of(int n, float& x1, float& y1, float& x2, float& y2) {
  int a = n % NA;
  int s = n / NA;
  int xx = s % NW;
  int yy = s / NW;
  float sx = (float)(xx * 16);
  float sy = (float)(yy * 16);
  x1 = c_anch[a][0] + sx; y1 = c_anch[a][1] + sy;
  x2 = c_anch[a][2] + sx; y2 = c_anch[a][3] + sy;
}

__device__ inline float iou1(float ax1, float ay1, float ax2, float ay2,
                             float gx1, float gy1, float gx2, float gy2) {
  float iw = fminf(ax2, gx2) - fmaxf(ax1, gx1) + 1.0f;
  iw = fmaxf(iw, 0.0f);
  float ih = fminf(ay2, gy2) - fmaxf(ay1, gy1) + 1.0f;
  ih = fmaxf(ih, 0.0f);
  float inter = iw * ih;
  float aa = (ax2 - ax1 + 1.0f) * (ay2 - ay1 + 1.0f);
  float ga = (gx2 - gx1 + 1.0f) * (gy2 - gy1 + 1.0f);
  return inter / (aa + ga - inter);
}

// ---------------- K1: per-gt max IoU, pruned to overlapping cells -------
// Anchors with no box overlap have iou exactly 0 and cannot affect the max
// (if the pruned max is 0, the reference's gt_max==0 -> 1e-5 replacement
// makes the best-check vacuous anyway). Per anchor type, overlapping shift
// cells form a rectangle; scan it with pow2-padded rows (shift/mask index
// math, conservative +/-1 cell margin). ~6.5K cells/gt vs 36864 brute.
__global__ __launch_bounds__(256) void k_gtmax(const float* __restrict__ gt,
                                               const int* __restrict__ nbox,
                                               float* __restrict__ gtmax) {
  int b = blockIdx.x / NK;
  int k = blockIdx.x % NK;
  if (k >= nbox[b]) {
    if (threadIdx.x == 0) gtmax[blockIdx.x] = -1.0f;  // unused downstream
    return;
  }
  const float* g = gt + ((size_t)b * NK + k) * 5;
  float gx1 = g[0], gy1 = g[1], gx2 = g[2], gy2 = g[3];
  float m = 0.0f;  // iou >= 0; empty scan -> 0 -> 1e-5 below
#pragma unroll
  for (int a = 0; a < NA; ++a) {
    float bx1 = c_anch[a][0], by1 = c_anch[a][1];
    float bx2 = c_anch[a][2], by2 = c_anch[a][3];
    // overlap needs 16*ix > gx1-1-bx2  and  16*ix < gx2+1-bx1 (cons. +/-1)
    int ix_lo = max(0, (int)floorf((gx1 - 1.0f - bx2) * 0.0625f) - 1);
    int ix_hi = min(NW - 1, (int)ceilf((gx2 + 1.0f - bx1) * 0.0625f) + 1);
    int iy_lo = max(0, (int)floorf((gy1 - 1.0f - by2) * 0.0625f) - 1);
    int iy_hi = min(NH - 1, (int)ceilf((gy2 + 1.0f - by1) * 0.0625f) + 1);
    if (ix_lo > ix_hi || iy_lo > iy_hi) continue;
    int nx = ix_hi - ix_lo + 1;
    int ny = iy_hi - iy_lo + 1;
    int lg = 32 - __clz(nx - 1);        // nx<=64 -> lg<=6 (nx==1 -> lg=0)
    int tot = ny << lg;
    unsigned mask = (1u << lg) - 1u;
    for (int c = threadIdx.x; c < tot; c += 256) {
      int ixo = c & mask;
      if (ixo >= nx) continue;
      int ix = ix_lo + ixo;
      int iy = iy_lo + (c >> lg);
      float sx = (float)(ix * 16), sy = (float)(iy * 16);
      m = fmaxf(m, iou1(bx1 + sx, by1 + sy, bx2 + sx, by2 + sy, gx1, gy1, gx2, gy2));
    }
  }
  for (int o = 1; o < 64; o <<= 1) m = fmaxf(m, __shfl_xor(m, o));
  __shared__ float ws4[4];
  if ((threadIdx.x & 63) == 0) ws4[threadIdx.x >> 6] = m;
  __syncthreads();
  if (threadIdx.x == 0) {
    m = fmaxf(fmaxf(ws4[0], ws4[1]), fmaxf(ws4[2], ws4[3]));
    if (m == 0.0f) m = 1e-5f;  // reference: gt_max==0 -> 1e-5
    gtmax[blockIdx.x] = m;
  }
}

// ---------------- K2: merged IoU + labels (gt/gtmax/areas in LDS) -------
__global__ __launch_bounds__(256) void k_label(const float* __restrict__ gt,
                                               const int* __restrict__ nbox,
                                               const float* __restrict__ gtmax,
                                               const float* __restrict__ iminfo,
                                               int* __restrict__ label,
                                               int* __restrict__ amax) {
  int b = blockIdx.x / BLK_PER_B;                // block-uniform batch index
  int n = (blockIdx.x % BLK_PER_B) * 256 + threadIdx.x;
  __shared__ float sg[NK * 5];
  __shared__ float sgm[NK];
  __shared__ float sga[NK];
  if (threadIdx.x < NK * 5) sg[threadIdx.x] = gt[(size_t)b * NK * 5 + threadIdx.x];
  if (threadIdx.x < NK) sgm[threadIdx.x] = gtmax[b * NK + threadIdx.x];
  __syncthreads();
  if (threadIdx.x < NK) {
    float* gg = sg + threadIdx.x * 5;
    sga[threadIdx.x] = (gg[2] - gg[0] + 1.0f) * (gg[3] - gg[1] + 1.0f);
  }
  __syncthreads();

  float ax1, ay1, ax2, ay2;
  anchor_of(n, ax1, ay1, ax2, ay2);
  float aa = (ax2 - ax1 + 1.0f) * (ay2 - ay1 + 1.0f);
  int m = nbox[b];
  float best = -2.0f;
  int bi = 0;
  bool isbest = false;
  for (int k = 0; k < m; ++k) {
    float iw = fminf(ax2, sg[k * 5 + 2]) - fmaxf(ax1, sg[k * 5]) + 1.0f;
    iw = fmaxf(iw, 0.0f);
    float ih = fminf(ay2, sg[k * 5 + 3]) - fmaxf(ay1, sg[k * 5 + 1]) + 1.0f;
    ih = fmaxf(ih, 0.0f);
    float inter = iw * ih;
    float ov = inter / (aa + sga[k] - inter);
    if (ov > best) { best = ov; bi = k; }   // first-max wins, like argmax
    if (ov == sgm[k]) isbest = true;
  }
  float imh = iminfo[0], imw = iminfo[1];  // im_info[0] used for all batches (matches ref)
  bool inside = (ax1 >= 0.0f) && (ay1 >= 0.0f) && (ax2 < imw) && (ay2 < imh);
  int lab = -1;
  if (inside) {
    if (best < 0.3f) lab = 0;
    if (isbest) lab = 1;
    if (best >= 0.7f) lab = 1;
  }
  int t = b * NN + n;
  label[t] = lab;
  amax[t] = bi;
}

// ---------------- K3: exact stable top-C subsampling -------------------
// One 1024-thread block per (batch, class). Two vectorized passes:
//   P1: count fg/bg + 4096-bucket LDS histogram of the 23-bit scores.
//   (parallel suffix-scan finds threshold bucket Bs and within-bucket rank r1)
//   P2: demote bucket<Bs inline; collect bucket==Bs ties into an LDS list.
// Exact stable top-r1 among ties by (v desc, idx asc) via O(L^2) rank.
// Equivalent to jax's stable rank of -uniform() (argsort-argsort).
__global__ __launch_bounds__(1024) void k_select(int* __restrict__ label,
                                                 float* __restrict__ numex) {
  int b = blockIdx.x >> 1;
  int cls = blockIdx.x & 1;  // 0 = fg, 1 = bg
  int base_lab = b * NN;
  int want = (cls == 0) ? 1 : 0;
  uint32_t kk0 = (cls == 0) ? KEY_FG.a : KEY_BG.a;
  uint32_t kk1 = (cls == 0) ? KEY_FG.b : KEY_BG.b;
  int tid = threadIdx.x;

  __shared__ unsigned h1s[4096];
  __shared__ unsigned listV[2048];
  __shared__ unsigned listI[2048];
  __shared__ unsigned waveTot[4];
  __shared__ int sFG, sBG, sBs, sR1, sCross;
  __shared__ unsigned sCnt;
  for (int i = tid; i < 4096; i += 1024) h1s[i] = 0;
  if (tid == 0) { sFG = 0; sBG = 0; sCross = -1; sCnt = 0; }
  __syncthreads();

  const int4* lab4 = (const int4*)(label + base_lab);

  // ---- Pass 1: fg/bg counts + level-1 histogram ----
  int cfg = 0, cbg = 0;
  for (int i = tid; i < NN / 4; i += 1024) {
    int4 L4 = lab4[i];
    int labs[4] = {L4.x, L4.y, L4.z, L4.w};
#pragma unroll
    for (int j = 0; j < 4; ++j) {
      int lab = labs[j];
      cfg += (lab == 1);
      cbg += (lab == 0);
      if (lab == want) {
        uint32_t v = rand23(kk0, kk1, (uint32_t)(base_lab + 4 * i + j));
        atomicAdd(&h1s[v >> 11], 1u);
      }
    }
  }
  for (int o = 1; o < 64; o <<= 1) { cfg += __shfl_xor(cfg, o); cbg += __shfl_xor(cbg, o); }
  if ((tid & 63) == 0) { atomicAdd(&sFG, cfg); atomicAdd(&sBG, cbg); }
  __syncthreads();

  int fg = sFG, bg = sBG;
  int fgk = min(fg, 128);
  int total, C;
  if (cls == 0) {
    total = fg; C = 128;
  } else {
    total = bg; C = 256 - fgk;
    if (tid == 0) numex[b] = (float)(fgk + min(bg, C));  // analytic num_examples
  }
  if (total <= C) return;  // keep all; uniform exit across block

  // ---- Parallel threshold: largest bucket Bs with suffix count >= C ----
  unsigned myChunk = 0, suf = 0;
  if (tid < 256) {
    for (int j = 0; j < 16; ++j) myChunk += h1s[tid * 16 + j];
    unsigned ss = myChunk;
    int lane = tid & 63;
#pragma unroll
    for (int o = 1; o < 64; o <<= 1) {
      unsigned t2 = __shfl_down(ss, o);
      if (lane + o < 64) ss += t2;
    }
    suf = ss;  // partial: suffix within this wave's chunk range
    if (lane == 0) waveTot[tid >> 6] = ss;
  }
  __syncthreads();
  if (tid < 256) {
    int w = tid >> 6;
    for (int w2 = w + 1; w2 < 4; ++w2) suf += waveTot[w2];
    // suf = S[16*tid] = count of scores in buckets >= 16*tid
    if (suf >= (unsigned)C) atomicMax(&sCross, tid);
  }
  __syncthreads();
  if (tid == sCross) {
    unsigned cum = suf - myChunk;  // S[16*(tid+1)]
    int i = tid * 16 + 15;
    for (;; --i) {
      unsigned c = h1s[i];
      if (cum + c >= (unsigned)C) break;
      cum += c;
    }
    sBs = i; sR1 = (int)((unsigned)C - cum);
  }
  __syncthreads();
  int Bs = sBs;
  unsigned r1 = (unsigned)sR1;

  // ---- Pass 2: demote bucket<Bs, collect bucket==Bs ties ----
  for (int i = tid; i < NN / 4; i += 1024) {
    int4 L4 = lab4[i];
    int labs[4] = {L4.x, L4.y, L4.z, L4.w};
#pragma unroll
    for (int j = 0; j < 4; ++j) {
      if (labs[j] == want) {
        int n = 4 * i + j;
        uint32_t v = rand23(kk0, kk1, (uint32_t)(base_lab + n));
        int bk = (int)(v >> 11);
        if (bk < Bs) {
          label[base_lab + n] = -1;
        } else if (bk == Bs) {
          unsigned p = atomicAdd(&sCnt, 1u);
          if (p < 2048u) { listV[p] = v; listI[p] = (unsigned)n; }
        }
      }
    }
  }
  __syncthreads();

  // ---- Exact stable top-r1 among ties: rank by (v desc, idx asc) ----
  unsigned L = min(sCnt, 2048u);
  for (unsigned i = tid; i < L; i += 1024) {
    unsigned vi = listV[i], xi = listI[i];
    unsigned rank = 0;
    for (unsigned j = 0; j < L; ++j) {
      unsigned vj = listV[j], xj = listI[j];
      rank += (vj > vi) || (vj == vi && xj < xi);
    }
    if (rank >= r1) label[base_lab + (int)xi] = -1;
  }
}

// ---------------- K4: write all four outputs (float4 stores) ----------
__global__ __launch_bounds__(256) void k_out(const float* __restrict__ gt,
                                             const int* __restrict__ label,
                                             const int* __restrict__ amax,
                                             const float* __restrict__ iminfo,
                                             const float* __restrict__ numex,
                                             float* __restrict__ out) {
  int q = blockIdx.x * 256 + threadIdx.x;
  if (q >= (int)(OUT_TGT / 4)) return;
  int xx4 = q & 15;
  int yy = (q >> 4) & 63;
  int ba = q >> 10;
  int a = ba % NA;
  int b = ba / NA;
  int xx0 = xx4 * 4;
  int yx0 = yy * NW + xx0;

  float imh = iminfo[0], imw = iminfo[1];
  float inv_ne = 1.0f / numex[b];

  float labf[4], iwv[4], owv[4], tg[4][4];
#pragma unroll
  for (int u = 0; u < 4; ++u) {
    int xx = xx0 + u;
    int n = (yy * NW + xx) * NA + a;
    int bn = b * NN + n;
    int lab = label[bn];
    labf[u] = (float)lab;
    float ax1, ay1, ax2, ay2;
    anchor_of(n, ax1, ay1, ax2, ay2);
    bool inside = (ax1 >= 0.0f) && (ay1 >= 0.0f) && (ax2 < imw) && (ay2 < imh);
    float t0 = 0.f, t1 = 0.f, t2 = 0.f, t3 = 0.f;
    if (inside) {
      const float* g = gt + ((size_t)b * NK + amax[bn]) * 5;
      float ew = ax2 - ax1 + 1.0f, eh = ay2 - ay1 + 1.0f;
      float ecx = ax1 + 0.5f * ew, ecy = ay1 + 0.5f * eh;
      float gw = g[2] - g[0] + 1.0f, gh = g[3] - g[1] + 1.0f;
      float gcx = g[0] + 0.5f * gw, gcy = g[1] + 0.5f * gh;
      t0 = (gcx - ecx) / ew;
      t1 = (gcy - ecy) / eh;
      t2 = logf(gw / ew);
      t3 = logf(gh / eh);
    }
    tg[0][u] = t0; tg[1][u] = t1; tg[2][u] = t2; tg[3][u] = t3;
    iwv[u] = (lab == 1) ? 1.0f : 0.0f;
    owv[u] = (lab >= 0) ? inv_ne : 0.0f;
  }

  *(float4*)(out + OUT_LAB + (size_t)ba * HWSZ + yx0) =
      make_float4(labf[0], labf[1], labf[2], labf[3]);
  size_t tb = OUT_TGT + ((size_t)b * NA * 4 + a * 4) * HWSZ + yx0;
#pragma unroll
  for (int d = 0; d < 4; ++d)
    *(float4*)(out + tb + (size_t)d * HWSZ) =
        make_float4(tg[d][0], tg[d][1], tg[d][2], tg[d][3]);
  size_t ib = OUT_INW + ((size_t)b * NA * 4 + a * 4) * HWSZ + yx0;
  float4 iw4 = make_float4(iwv[0], iwv[1], iwv[2], iwv[3]);
#pragma unroll
  for (int d = 0; d < 4; ++d) *(float4*)(out + ib + (size_t)d * HWSZ) = iw4;
  size_t ob = OUT_OUTW + ((size_t)b * NA * 4 + a * 4) * HWSZ + yx0;
  float4 ow4 = make_float4(owv[0], owv[1], owv[2], owv[3]);
#pragma unroll
  for (int d = 0; d < 4; ++d) *(float4*)(out + ob + (size_t)d * HWSZ) = ow4;
}

extern "C" void kernel_launch(void* const* d_in, const int* in_sizes, int n_in,
                              void* d_out, int out_size, void* d_ws, size_t ws_size,
                              hipStream_t stream) {
  (void)in_sizes; (void)n_in; (void)out_size; (void)ws_size;
  const float* gt     = (const float*)d_in[1];  // (B,K,5)
  const float* iminfo = (const float*)d_in[2];  // (B,3)
  const int*   nbox   = (const int*)d_in[3];    // (B,)
  float* out = (float*)d_out;
  char* ws = (char*)d_ws;

  int*   amax  = (int*)(ws + OFF_AMAX);
  int*   label = (int*)(ws + OFF_LABEL);
  float* gtmax = (float*)(ws + OFF_GTMAX);
  float* numex = (float*)(ws + OFF_NUMEX);

  k_gtmax<<<NBATCH * NK, 256, 0, stream>>>(gt, nbox, gtmax);
  k_label<<<BN / 256, 256, 0, stream>>>(gt, nbox, gtmax, iminfo, label, amax);
  k_select<<<2 * NBATCH, 1024, 0, stream>>>(label, numex);
  k_out<<<(int)(OUT_TGT / 4 / 256), 256, 0, stream>>>(gt, label, amax, iminfo, numex, out);
}

// Round 5
// 162.657 us; speedup vs baseline: 31.9601x; 1.2004x over previous
//
#include <hip/hip_runtime.h>
#include <stdint.h>

// Exactness: the numpy/jax reference does plain IEEE f32 ops (no FMA
// contraction). hipcc defaults to -ffp-contract=fast; disable globally so
// IoU values match the reference bit-for-bit (labels depend on exact
// comparisons vs 0.3/0.7 and on ov == gt_max equality).
#pragma clang fp contract(off)

#define NBATCH 32
#define NK 50
#define NH 64
#define NW 64
#define NA 9
#define NN (NH * NW * NA)   // 36864 anchors per batch
#define BN (NBATCH * NN)    // 1179648
#define HWSZ (NH * NW)      // 4096
#define BLK_PER_B (NN / 256)  // 144 label-blocks per batch

// ---------------- workspace layout (bytes) ----------------
// pk[t] = (v23 << 2) | (lab+1): 23-bit threefry score + 2-bit label code,
// computed once in k_label (massively parallel) so k_select never hashes.
constexpr size_t OFF_AMAX  = 0;
constexpr size_t OFF_PK    = OFF_AMAX + (size_t)BN * 4;
constexpr size_t OFF_GTMAX = OFF_PK + (size_t)BN * 4;
constexpr size_t OFF_NUMEX = OFF_GTMAX + (size_t)NBATCH * NK * 4;

// ---------------- output layout (f32 elements) ----------------
constexpr size_t OUT_LAB  = 0;
constexpr size_t OUT_TGT  = (size_t)NBATCH * NA * HWSZ;                 // 1179648
constexpr size_t OUT_INW  = OUT_TGT + (size_t)NBATCH * NA * 4 * HWSZ;   // 5898240
constexpr size_t OUT_OUTW = OUT_INW + (size_t)NBATCH * NA * 4 * HWSZ;   // 10616832

// 9 base anchors, py-faster-rcnn generate_anchors(16, (0.5,1,2), (8,16,32)),
// ratio-major scale-minor. All integer-valued -> exact in f32.
__constant__ float c_anch[NA][4] = {
    {-84.f, -40.f, 99.f, 55.f},    {-176.f, -88.f, 191.f, 103.f},
    {-360.f, -184.f, 375.f, 199.f}, {-56.f, -56.f, 71.f, 71.f},
    {-120.f, -120.f, 135.f, 135.f}, {-248.f, -248.f, 263.f, 263.f},
    {-36.f, -80.f, 51.f, 95.f},    {-80.f, -168.f, 95.f, 183.f},
    {-168.f, -344.f, 183.f, 359.f}};

// ---------------- Threefry-2x32 (JAX convention) ----------------
struct TF2 { uint32_t a, b; };

__host__ __device__ constexpr uint32_t rotl32(uint32_t x, int d) {
  return (x << d) | (x >> (32 - d));
}

__host__ __device__ constexpr TF2 threefry2x32(uint32_t k0, uint32_t k1,
                                               uint32_t x0, uint32_t x1) {
  uint32_t ks2 = k0 ^ k1 ^ 0x1BD11BDAu;
  x0 += k0; x1 += k1;
  x0 += x1; x1 = rotl32(x1, 13); x1 ^= x0;
  x0 += x1; x1 = rotl32(x1, 15); x1 ^= x0;
  x0 += x1; x1 = rotl32(x1, 26); x1 ^= x0;
  x0 += x1; x1 = rotl32(x1, 6);  x1 ^= x0;
  x0 += k1; x1 += ks2 + 1u;
  x0 += x1; x1 = rotl32(x1, 17); x1 ^= x0;
  x0 += x1; x1 = rotl32(x1, 29); x1 ^= x0;
  x0 += x1; x1 = rotl32(x1, 16); x1 ^= x0;
  x0 += x1; x1 = rotl32(x1, 24); x1 ^= x0;
  x0 += ks2; x1 += k0 + 2u;
  x0 += x1; x1 = rotl32(x1, 13); x1 ^= x0;
  x0 += x1; x1 = rotl32(x1, 15); x1 ^= x0;
  x0 += x1; x1 = rotl32(x1, 26); x1 ^= x0;
  x0 += x1; x1 = rotl32(x1, 6);  x1 ^= x0;
  x0 += k0; x1 += k1 + 3u;
  x0 += x1; x1 = rotl32(x1, 17); x1 ^= x0;
  x0 += x1; x1 = rotl32(x1, 29); x1 ^= x0;
  x0 += x1; x1 = rotl32(x1, 16); x1 ^= x0;
  x0 += x1; x1 = rotl32(x1, 24); x1 ^= x0;
  x0 += k1; x1 += ks2 + 4u;
  x0 += x1; x1 = rotl32(x1, 13); x1 ^= x0;
  x0 += x1; x1 = rotl32(x1, 15); x1 ^= x0;
  x0 += x1; x1 = rotl32(x1, 26); x1 ^= x0;
  x0 += x1; x1 = rotl32(x1, 6);  x1 ^= x0;
  x0 += ks2; x1 += k0 + 5u;
  return TF2{x0, x1};
}

// jax.random.key(42) = (0,42); split with jax_threefry_partitionable=True:
// subkey i = threefry(key, counter=(0, i)).
constexpr TF2 KEY_FG = threefry2x32(0u, 42u, 0u, 0u);
constexpr TF2 KEY_BG = threefry2x32(0u, 42u, 0u, 1u);

// 32-bit draw at flat index i (partitionable): bits = out.a ^ out.b of
// threefry(key, hi32(i)=0, lo32(i)=i). Ranking score for uniform() is
// monotone+injective in bits>>9, so compare the 23-bit value directly.
__device__ inline uint32_t rand23(uint32_t k0, uint32_t k1, uint32_t idx) {
  TF2 r = threefry2x32(k0, k1, 0u, idx);
  return (r.a ^ r.b) >> 9;
}

// ---------------- geometry ----------------
__device__ inline void anchor_of(int n, float& x1, float& y1, float& x2, float& y2) {
  int a = n % NA;
  int s = n / NA;
  int xx = s % NW;
  int yy = s / NW;
  float sx = (float)(xx * 16);
  float sy = (float)(yy * 16);
  x1 = c_anch[a][0] + sx; y1 = c_anch[a][1] + sy;
  x2 = c_anch[a][2] + sx; y2 = c_anch[a][3] + sy;
}

__device__ inline float iou1(float ax1, float ay1, float ax2, float ay2,
                             float gx1, float gy1, float gx2, float gy2) {
  float iw = fminf(ax2, gx2) - fmaxf(ax1, gx1) + 1.0f;
  iw = fmaxf(iw, 0.0f);
  float ih = fminf(ay2, gy2) - fmaxf(ay1, gy1) + 1.0f;
  ih = fmaxf(ih, 0.0f);
  float inter = iw * ih;
  float aa = (ax2 - ax1 + 1.0f) * (ay2 - ay1 + 1.0f);
  float ga = (gx2 - gx1 + 1.0f) * (gy2 - gy1 + 1.0f);
  return inter / (aa + ga - inter);
}

// ---------------- K1: per-gt max IoU, pruned to overlapping cells -------
// Anchors with no box overlap have iou exactly 0 and cannot affect the max
// (if the pruned max is 0, the reference's gt_max==0 -> 1e-5 replacement
// makes the best-check vacuous anyway). Per anchor type, overlapping shift
// cells form a rectangle; scan it with pow2-padded rows (shift/mask index
// math, conservative +/-1 cell margin). ~6.5K cells/gt vs 36864 brute.
__global__ __launch_bounds__(256) void k_gtmax(const float* __restrict__ gt,
                                               const int* __restrict__ nbox,
                                               float* __restrict__ gtmax) {
  int b = blockIdx.x / NK;
  int k = blockIdx.x % NK;
  if (k >= nbox[b]) {
    if (threadIdx.x == 0) gtmax[blockIdx.x] = -1.0f;  // unused downstream
    return;
  }
  const float* g = gt + ((size_t)b * NK + k) * 5;
  float gx1 = g[0], gy1 = g[1], gx2 = g[2], gy2 = g[3];
  float m = 0.0f;  // iou >= 0; empty scan -> 0 -> 1e-5 below
#pragma unroll
  for (int a = 0; a < NA; ++a) {
    float bx1 = c_anch[a][0], by1 = c_anch[a][1];
    float bx2 = c_anch[a][2], by2 = c_anch[a][3];
    // overlap needs 16*ix > gx1-1-bx2  and  16*ix < gx2+1-bx1 (cons. +/-1)
    int ix_lo = max(0, (int)floorf((gx1 - 1.0f - bx2) * 0.0625f) - 1);
    int ix_hi = min(NW - 1, (int)ceilf((gx2 + 1.0f - bx1) * 0.0625f) + 1);
    int iy_lo = max(0, (int)floorf((gy1 - 1.0f - by2) * 0.0625f) - 1);
    int iy_hi = min(NH - 1, (int)ceilf((gy2 + 1.0f - by1) * 0.0625f) + 1);
    if (ix_lo > ix_hi || iy_lo > iy_hi) continue;
    int nx = ix_hi - ix_lo + 1;
    int ny = iy_hi - iy_lo + 1;
    int lg = 32 - __clz(nx - 1);        // nx<=64 -> lg<=6 (nx==1 -> lg=0)
    int tot = ny << lg;
    unsigned mask = (1u << lg) - 1u;
    for (int c = threadIdx.x; c < tot; c += 256) {
      int ixo = c & mask;
      if (ixo >= nx) continue;
      int ix = ix_lo + ixo;
      int iy = iy_lo + (c >> lg);
      float sx = (float)(ix * 16), sy = (float)(iy * 16);
      m = fmaxf(m, iou1(bx1 + sx, by1 + sy, bx2 + sx, by2 + sy, gx1, gy1, gx2, gy2));
    }
  }
  for (int o = 1; o < 64; o <<= 1) m = fmaxf(m, __shfl_xor(m, o));
  __shared__ float ws4[4];
  if ((threadIdx.x & 63) == 0) ws4[threadIdx.x >> 6] = m;
  __syncthreads();
  if (threadIdx.x == 0) {
    m = fmaxf(fmaxf(ws4[0], ws4[1]), fmaxf(ws4[2], ws4[3]));
    if (m == 0.0f) m = 1e-5f;  // reference: gt_max==0 -> 1e-5
    gtmax[blockIdx.x] = m;
  }
}

// ---------------- K2: IoU + labels + threefry score, packed write -------
// pk = (v23 << 2) | (lab+1). Threefry computed HERE (4608 blocks, ~2us
// GPU-wide) instead of k_select (64 blocks, was ~30us under divergence).
__global__ __launch_bounds__(256) void k_label(const float* __restrict__ gt,
                                               const int* __restrict__ nbox,
                                               const float* __restrict__ gtmax,
                                               const float* __restrict__ iminfo,
                                               unsigned* __restrict__ pkarr,
                                               int* __restrict__ amax) {
  int b = blockIdx.x / BLK_PER_B;                // block-uniform batch index
  int n = (blockIdx.x % BLK_PER_B) * 256 + threadIdx.x;
  __shared__ float sg[NK * 5];
  __shared__ float sgm[NK];
  __shared__ float sga[NK];
  if (threadIdx.x < NK * 5) sg[threadIdx.x] = gt[(size_t)b * NK * 5 + threadIdx.x];
  if (threadIdx.x < NK) sgm[threadIdx.x] = gtmax[b * NK + threadIdx.x];
  __syncthreads();
  if (threadIdx.x < NK) {
    float* gg = sg + threadIdx.x * 5;
    sga[threadIdx.x] = (gg[2] - gg[0] + 1.0f) * (gg[3] - gg[1] + 1.0f);
  }
  __syncthreads();

  float ax1, ay1, ax2, ay2;
  anchor_of(n, ax1, ay1, ax2, ay2);
  float aa = (ax2 - ax1 + 1.0f) * (ay2 - ay1 + 1.0f);
  int m = nbox[b];
  float best = -2.0f;
  int bi = 0;
  bool isbest = false;
  for (int k = 0; k < m; ++k) {
    float iw = fminf(ax2, sg[k * 5 + 2]) - fmaxf(ax1, sg[k * 5]) + 1.0f;
    iw = fmaxf(iw, 0.0f);
    float ih = fminf(ay2, sg[k * 5 + 3]) - fmaxf(ay1, sg[k * 5 + 1]) + 1.0f;
    ih = fmaxf(ih, 0.0f);
    float inter = iw * ih;
    float ov = inter / (aa + sga[k] - inter);
    if (ov > best) { best = ov; bi = k; }   // first-max wins, like argmax
    if (ov == sgm[k]) isbest = true;
  }
  float imh = iminfo[0], imw = iminfo[1];  // im_info[0] used for all batches (matches ref)
  bool inside = (ax1 >= 0.0f) && (ay1 >= 0.0f) && (ax2 < imw) && (ay2 < imh);
  int lab = -1;
  if (inside) {
    if (best < 0.3f) lab = 0;
    if (isbest) lab = 1;
    if (best >= 0.7f) lab = 1;
  }
  int t = b * NN + n;
  // Score with this anchor's own class key (branchless select; lab==-1
  // value is never used downstream).
  uint32_t kk0 = (lab == 1) ? KEY_FG.a : KEY_BG.a;
  uint32_t kk1 = (lab == 1) ? KEY_FG.b : KEY_BG.b;
  uint32_t v = rand23(kk0, kk1, (uint32_t)t);
  pkarr[t] = (v << 2) | (uint32_t)(lab + 1);
  amax[t] = bi;
}

// ---------------- K3: exact stable top-C subsampling -------------------
// One 1024-thread block per (batch, class). Reads pre-hashed pk words:
//   P1: count fg/bg + 4096-bucket LDS histogram (bucket = pk>>13).
//   (parallel suffix-scan finds threshold bucket Bs and within-bucket rank r1)
//   P2: demote bucket<Bs inline; collect bucket==Bs ties into an LDS list.
// Exact stable top-r1 among ties by (v desc, idx asc) via O(L^2) rank.
// Benign race note: concurrent fg-block demotions only move the bg block's
// observed fg count between fg and fgk=min(fg,128); min(.,128) is invariant,
// so C and numex are unaffected. Demotes only clear the 2 code bits.
__global__ __launch_bounds__(1024) void k_select(unsigned* __restrict__ pkarr,
                                                 float* __restrict__ numex) {
  int b = blockIdx.x >> 1;
  int cls = blockIdx.x & 1;  // 0 = fg, 1 = bg
  int base_lab = b * NN;
  unsigned wantcode = (cls == 0) ? 2u : 1u;
  int tid = threadIdx.x;

  __shared__ unsigned h1s[4096];
  __shared__ unsigned listV[2048];
  __shared__ unsigned listI[2048];
  __shared__ unsigned waveTot[4];
  __shared__ int sFG, sBG, sBs, sR1, sCross;
  __shared__ unsigned sCnt;
  for (int i = tid; i < 4096; i += 1024) h1s[i] = 0;
  if (tid == 0) { sFG = 0; sBG = 0; sCross = -1; sCnt = 0; }
  __syncthreads();

  const uint4* pk4 = (const uint4*)(pkarr + base_lab);

  // ---- Pass 1: fg/bg counts + level-1 histogram ----
  int cfg = 0, cbg = 0;
  for (int i = tid; i < NN / 4; i += 1024) {
    uint4 P4 = pk4[i];
    unsigned pks[4] = {P4.x, P4.y, P4.z, P4.w};
#pragma unroll
    for (int j = 0; j < 4; ++j) {
      unsigned code = pks[j] & 3u;
      cfg += (code == 2u);
      cbg += (code == 1u);
      if (code == wantcode) atomicAdd(&h1s[pks[j] >> 13], 1u);
    }
  }
  for (int o = 1; o < 64; o <<= 1) { cfg += __shfl_xor(cfg, o); cbg += __shfl_xor(cbg, o); }
  if ((tid & 63) == 0) { atomicAdd(&sFG, cfg); atomicAdd(&sBG, cbg); }
  __syncthreads();

  int fg = sFG, bg = sBG;
  int fgk = min(fg, 128);
  int total, C;
  if (cls == 0) {
    total = fg; C = 128;
  } else {
    total = bg; C = 256 - fgk;
    if (tid == 0) numex[b] = (float)(fgk + min(bg, C));  // analytic num_examples
  }
  if (total <= C) return;  // keep all; uniform exit across block

  // ---- Parallel threshold: largest bucket Bs with suffix count >= C ----
  unsigned myChunk = 0, suf = 0;
  if (tid < 256) {
    for (int j = 0; j < 16; ++j) myChunk += h1s[tid * 16 + j];
    unsigned ss = myChunk;
    int lane = tid & 63;
#pragma unroll
    for (int o = 1; o < 64; o <<= 1) {
      unsigned t2 = __shfl_down(ss, o);
      if (lane + o < 64) ss += t2;
    }
    suf = ss;  // partial: suffix within this wave's chunk range
    if (lane == 0) waveTot[tid >> 6] = ss;
  }
  __syncthreads();
  if (tid < 256) {
    int w = tid >> 6;
    for (int w2 = w + 1; w2 < 4; ++w2) suf += waveTot[w2];
    // suf = S[16*tid] = count of scores in buckets >= 16*tid
    if (suf >= (unsigned)C) atomicMax(&sCross, tid);
  }
  __syncthreads();
  if (tid == sCross) {
    unsigned cum = suf - myChunk;  // S[16*(tid+1)]
    int i = tid * 16 + 15;
    for (;; --i) {
      unsigned c = h1s[i];
      if (cum + c >= (unsigned)C) break;
      cum += c;
    }
    sBs = i; sR1 = (int)((unsigned)C - cum);
  }
  __syncthreads();
  int Bs = sBs;
  unsigned r1 = (unsigned)sR1;

  // ---- Pass 2: demote bucket<Bs, collect bucket==Bs ties ----
  for (int i = tid; i < NN / 4; i += 1024) {
    uint4 P4 = pk4[i];
    unsigned pks[4] = {P4.x, P4.y, P4.z, P4.w};
#pragma unroll
    for (int j = 0; j < 4; ++j) {
      if ((pks[j] & 3u) == wantcode) {
        unsigned v = pks[j] >> 2;
        int bk = (int)(v >> 11);
        int n = 4 * i + j;
        if (bk < Bs) {
          pkarr[base_lab + n] = pks[j] & ~3u;  // lab -> -1, keep v bits
        } else if (bk == Bs) {
          unsigned p = atomicAdd(&sCnt, 1u);
          if (p < 2048u) { listV[p] = v; listI[p] = (unsigned)n; }
        }
      }
    }
  }
  __syncthreads();

  // ---- Exact stable top-r1 among ties: rank by (v desc, idx asc) ----
  unsigned L = min(sCnt, 2048u);
  for (unsigned i = tid; i < L; i += 1024) {
    unsigned vi = listV[i], xi = listI[i];
    unsigned rank = 0;
    for (unsigned j = 0; j < L; ++j) {
      unsigned vj = listV[j], xj = listI[j];
      rank += (vj > vi) || (vj == vi && xj < xi);
    }
    if (rank >= r1) pkarr[base_lab + (int)xi] = vi << 2;  // demote tie
  }
}

// ---------------- K4: write all four outputs (float4 stores) ----------
__global__ __launch_bounds__(256) void k_out(const float* __restrict__ gt,
                                             const unsigned* __restrict__ pkarr,
                                             const int* __restrict__ amax,
                                             const float* __restrict__ iminfo,
                                             const float* __restrict__ numex,
                                             float* __restrict__ out) {
  int q = blockIdx.x * 256 + threadIdx.x;
  if (q >= (int)(OUT_TGT / 4)) return;
  int xx4 = q & 15;
  int yy = (q >> 4) & 63;
  int ba = q >> 10;
  int a = ba % NA;
  int b = ba / NA;
  int xx0 = xx4 * 4;
  int yx0 = yy * NW + xx0;

  float imh = iminfo[0], imw = iminfo[1];
  float inv_ne = 1.0f / numex[b];

  float labf[4], iwv[4], owv[4], tg[4][4];
#pragma unroll
  for (int u = 0; u < 4; ++u) {
    int xx = xx0 + u;
    int n = (yy * NW + xx) * NA + a;
    int bn = b * NN + n;
    int lab = (int)(pkarr[bn] & 3u) - 1;
    labf[u] = (float)lab;
    float ax1, ay1, ax2, ay2;
    anchor_of(n, ax1, ay1, ax2, ay2);
    bool inside = (ax1 >= 0.0f) && (ay1 >= 0.0f) && (ax2 < imw) && (ay2 < imh);
    float t0 = 0.f, t1 = 0.f, t2 = 0.f, t3 = 0.f;
    if (inside) {
      const float* g = gt + ((size_t)b * NK + amax[bn]) * 5;
      float ew = ax2 - ax1 + 1.0f, eh = ay2 - ay1 + 1.0f;
      float ecx = ax1 + 0.5f * ew, ecy = ay1 + 0.5f * eh;
      float gw = g[2] - g[0] + 1.0f, gh = g[3] - g[1] + 1.0f;
      float gcx = g[0] + 0.5f * gw, gcy = g[1] + 0.5f * gh;
      t0 = (gcx - ecx) / ew;
      t1 = (gcy - ecy) / eh;
      t2 = logf(gw / ew);
      t3 = logf(gh / eh);
    }
    tg[0][u] = t0; tg[1][u] = t1; tg[2][u] = t2; tg[3][u] = t3;
    iwv[u] = (lab == 1) ? 1.0f : 0.0f;
    owv[u] = (lab >= 0) ? inv_ne : 0.0f;
  }

  *(float4*)(out + OUT_LAB + (size_t)ba * HWSZ + yx0) =
      make_float4(labf[0], labf[1], labf[2], labf[3]);
  size_t tb = OUT_TGT + ((size_t)b * NA * 4 + a * 4) * HWSZ + yx0;
#pragma unroll
  for (int d = 0; d < 4; ++d)
    *(float4*)(out + tb + (size_t)d * HWSZ) =
        make_float4(tg[d][0], tg[d][1], tg[d][2], tg[d][3]);
  size_t ib = OUT_INW + ((size_t)b * NA * 4 + a * 4) * HWSZ + yx0;
  float4 iw4 = make_float4(iwv[0], iwv[1], iwv[2], iwv[3]);
#pragma unroll
  for (int d = 0; d < 4; ++d) *(float4*)(out + ib + (size_t)d * HWSZ) = iw4;
  size_t ob = OUT_OUTW + ((size_t)b * NA * 4 + a * 4) * HWSZ + yx0;
  float4 ow4 = make_float4(owv[0], owv[1], owv[2], owv[3]);
#pragma unroll
  for (int d = 0; d < 4; ++d) *(float4*)(out + ob + (size_t)d * HWSZ) = ow4;
}

extern "C" void kernel_launch(void* const* d_in, const int* in_sizes, int n_in,
                              void* d_out, int out_size, void* d_ws, size_t ws_size,
                              hipStream_t stream) {
  (void)in_sizes; (void)n_in; (void)out_size; (void)ws_size;
  const float* gt     = (const float*)d_in[1];  // (B,K,5)
  const float* iminfo = (const float*)d_in[2];  // (B,3)
  const int*   nbox   = (const int*)d_in[3];    // (B,)
  float* out = (float*)d_out;
  char* ws = (char*)d_ws;

  int*      amax  = (int*)(ws + OFF_AMAX);
  unsigned* pkarr = (unsigned*)(ws + OFF_PK);
  float*    gtmax = (float*)(ws + OFF_GTMAX);
  float*    numex = (float*)(ws + OFF_NUMEX);

  k_gtmax<<<NBATCH * NK, 256, 0, stream>>>(gt, nbox, gtmax);
  k_label<<<BN / 256, 256, 0, stream>>>(gt, nbox, gtmax, iminfo, pkarr, amax);
  k_select<<<2 * NBATCH, 1024, 0, stream>>>(pkarr, numex);
  k_out<<<(int)(OUT_TGT / 4 / 256), 256, 0, stream>>>(gt, pkarr, amax, iminfo, numex, out);
}